// Round 2
// baseline (1008.325 us; speedup 1.0000x reference)
//
#include <hip/hip_runtime.h>

#define NNODES 100000
#define NEDGES 1600000
#define DINP   128
#define HDIM   64
#define NLAYERS 2

// ---------------------------------------------------------------------------
// h0 = x @ W_emb + b_emb        (N x 128) @ (128 x 64)
// block = 256 threads -> 32 rows; each thread owns 8 rows x 1 col
// ---------------------------------------------------------------------------
__global__ __launch_bounds__(256) void emb_kernel(
    const float* __restrict__ x, const float* __restrict__ Wemb,
    const float* __restrict__ bemb, float* __restrict__ h)
{
    __shared__ float sW[DINP * HDIM];   // 32 KB
    __shared__ float sx[32][DINP];      // 16 KB
    const int tid = threadIdx.x;

    for (int i = tid; i < DINP * HDIM; i += 256) sW[i] = Wemb[i];

    const int row0 = blockIdx.x * 32;   // N % 32 == 0 (100000/32 = 3125)
    for (int i = tid; i < 32 * DINP; i += 256) {
        int r = i >> 7, c = i & 127;
        sx[r][c] = x[(size_t)(row0 + r) * DINP + c];
    }
    __syncthreads();

    const int j  = tid & 63;
    const int rg = tid >> 6;            // 0..3 -> rows rg*8 .. rg*8+7
    float acc[8];
    const float bj = bemb[j];
#pragma unroll
    for (int r = 0; r < 8; ++r) acc[r] = bj;

    for (int k = 0; k < DINP; ++k) {
        float w = sW[k * HDIM + j];
#pragma unroll
        for (int r = 0; r < 8; ++r)
            acc[r] += sx[rg * 8 + r][k] * w;
    }
#pragma unroll
    for (int r = 0; r < 8; ++r)
        h[(size_t)(row0 + rg * 8 + r) * HDIM + j] = acc[r];
}

// ---------------------------------------------------------------------------
// deg_w[v] = sum of edge_attr over edges with dst == v   (layer-invariant)
// ---------------------------------------------------------------------------
__global__ __launch_bounds__(256) void deg_kernel(
    const int* __restrict__ dst, const float* __restrict__ attr,
    float* __restrict__ degw)
{
    int e = blockIdx.x * 256 + threadIdx.x;   // E % 256 == 0
    atomicAdd(&degw[dst[e]], attr[e]);
}

// ---------------------------------------------------------------------------
// agg[dst] += w * h[src]   — one wave per edge, lane = column
// ---------------------------------------------------------------------------
__global__ __launch_bounds__(256) void scatter_kernel(
    const int* __restrict__ src, const int* __restrict__ dst,
    const float* __restrict__ attr, const float* __restrict__ h,
    float* __restrict__ agg)
{
    int gid  = blockIdx.x * 256 + threadIdx.x;
    int e    = gid >> 6;
    int lane = gid & 63;
    int s = src[e], d = dst[e];
    float w = attr[e];
    atomicAdd(&agg[(size_t)d * HDIM + lane], w * h[(size_t)s * HDIM + lane]);
}

// ---------------------------------------------------------------------------
// h = relu(agg @ W1 + h @ W3 - deg ⊙ (h @ W2) + deg·b1 + b3)   (in place)
// block = 256 threads -> 32 rows; each thread owns 8 rows x 1 col
// ---------------------------------------------------------------------------
__global__ __launch_bounds__(256) void dense_kernel(
    const float* __restrict__ hin, const float* __restrict__ agg,
    const float* __restrict__ degw,
    const float* __restrict__ W1, const float* __restrict__ b1,
    const float* __restrict__ W2, const float* __restrict__ W3,
    const float* __restrict__ b3, float* __restrict__ hout)
{
    __shared__ float sW1[HDIM * HDIM], sW2[HDIM * HDIM], sW3[HDIM * HDIM]; // 48 KB
    __shared__ float sh[32][HDIM], sg[32][HDIM];                           // 16 KB
    const int tid = threadIdx.x;

    for (int i = tid; i < HDIM * HDIM; i += 256) {
        sW1[i] = W1[i]; sW2[i] = W2[i]; sW3[i] = W3[i];
    }
    const int row0 = blockIdx.x * 32;
    for (int i = tid; i < 32 * HDIM; i += 256) {
        int r = i >> 6, c = i & 63;
        size_t g = (size_t)(row0 + r) * HDIM + c;
        sh[r][c] = hin[g];
        sg[r][c] = agg[g];
    }
    __syncthreads();

    const int j  = tid & 63;
    const int rg = tid >> 6;
    float t1[8], t2[8], t3[8];
#pragma unroll
    for (int r = 0; r < 8; ++r) { t1[r] = 0.f; t2[r] = 0.f; t3[r] = 0.f; }

    for (int k = 0; k < HDIM; ++k) {
        float w1 = sW1[k * HDIM + j];
        float w2 = sW2[k * HDIM + j];
        float w3 = sW3[k * HDIM + j];
#pragma unroll
        for (int r = 0; r < 8; ++r) {
            float hv = sh[rg * 8 + r][k];
            float gv = sg[rg * 8 + r][k];
            t1[r] += gv * w1;
            t2[r] += hv * w2;
            t3[r] += hv * w3;
        }
    }

    const float b1j = b1[j], b3j = b3[j];
#pragma unroll
    for (int r = 0; r < 8; ++r) {
        int row = row0 + rg * 8 + r;
        float deg = degw[row];
        float o = t1[r] + t3[r] - deg * t2[r] + deg * b1j + b3j;
        hout[(size_t)row * HDIM + j] = fmaxf(o, 0.f);
    }
}

// ---------------------------------------------------------------------------
extern "C" void kernel_launch(void* const* d_in, const int* in_sizes, int n_in,
                              void* d_out, int out_size, void* d_ws, size_t ws_size,
                              hipStream_t stream)
{
    const float* x    = (const float*)d_in[0];
    const int*   eidx = (const int*)  d_in[1];   // (2, E) int
    const float* attr = (const float*)d_in[2];
    // d_in[3] = batch (unused: single segment, not in output)
    const float* Wemb = (const float*)d_in[4];
    const float* bemb = (const float*)d_in[5];
    const float* W1   = (const float*)d_in[6];
    const float* b1   = (const float*)d_in[7];
    const float* W2   = (const float*)d_in[8];
    const float* W3   = (const float*)d_in[9];
    const float* b3   = (const float*)d_in[10];

    float* h    = (float*)d_out;                       // N x 64, updated in place
    float* agg  = (float*)d_ws;                        // N x 64
    float* degw = agg + (size_t)NNODES * HDIM;         // N

    const int* srcI = eidx;
    const int* dstI = eidx + NEDGES;

    hipMemsetAsync(degw, 0, NNODES * sizeof(float), stream);

    emb_kernel<<<NNODES / 32, 256, 0, stream>>>(x, Wemb, bemb, h);
    deg_kernel<<<NEDGES / 256, 256, 0, stream>>>(dstI, attr, degw);

    for (int l = 0; l < NLAYERS; ++l) {
        hipMemsetAsync(agg, 0, (size_t)NNODES * HDIM * sizeof(float), stream);
        scatter_kernel<<<(size_t)NEDGES * 64 / 256, 256, 0, stream>>>(
            srcI, dstI, attr, h, agg);
        dense_kernel<<<NNODES / 32, 256, 0, stream>>>(
            h, agg, degw,
            W1 + (size_t)l * HDIM * HDIM, b1 + (size_t)l * HDIM,
            W2 + (size_t)l * HDIM * HDIM, W3 + (size_t)l * HDIM * HDIM,
            b3 + (size_t)l * HDIM, h);
    }
}

// Round 3
// 795.314 us; speedup vs baseline: 1.2678x; 1.2678x over previous
//
#include <hip/hip_runtime.h>

#define NNODES 100000
#define NEDGES 1600000
#define DINP   128
#define HDIM   64
#define NLAYERS 2
#define SCAN_THREADS 1024
#define SCAN_CHUNK   98   // 1024*98 = 100352 >= 100000

// ---------------------------------------------------------------------------
// h0 = x @ W_emb + b_emb        (N x 128) @ (128 x 64)
// ---------------------------------------------------------------------------
__global__ __launch_bounds__(256) void emb_kernel(
    const float* __restrict__ x, const float* __restrict__ Wemb,
    const float* __restrict__ bemb, float* __restrict__ h)
{
    __shared__ float sW[DINP * HDIM];   // 32 KB
    __shared__ float sx[32][DINP];      // 16 KB
    const int tid = threadIdx.x;

    for (int i = tid; i < DINP * HDIM; i += 256) sW[i] = Wemb[i];

    const int row0 = blockIdx.x * 32;   // 100000 / 32 = 3125
    for (int i = tid; i < 32 * DINP; i += 256) {
        int r = i >> 7, c = i & 127;
        sx[r][c] = x[(size_t)(row0 + r) * DINP + c];
    }
    __syncthreads();

    const int j  = tid & 63;
    const int rg = tid >> 6;
    float acc[8];
    const float bj = bemb[j];
#pragma unroll
    for (int r = 0; r < 8; ++r) acc[r] = bj;

    for (int k = 0; k < DINP; ++k) {
        float w = sW[k * HDIM + j];
#pragma unroll
        for (int r = 0; r < 8; ++r)
            acc[r] += sx[rg * 8 + r][k] * w;
    }
#pragma unroll
    for (int r = 0; r < 8; ++r)
        h[(size_t)(row0 + rg * 8 + r) * HDIM + j] = acc[r];
}

// ---------------------------------------------------------------------------
// CSR build: histogram -> scan -> fill (dst is layer-invariant, built once)
// ---------------------------------------------------------------------------
__global__ __launch_bounds__(256) void hist_kernel(
    const int* __restrict__ dst, int* __restrict__ counts)
{
    int e = blockIdx.x * 256 + threadIdx.x;   // E % 256 == 0
    atomicAdd(&counts[dst[e]], 1);
}

// counts -> rowptr (exclusive prefix); counts becomes the fill cursor
__global__ __launch_bounds__(SCAN_THREADS) void scan_kernel(
    int* __restrict__ counts, int* __restrict__ rowptr)
{
    __shared__ int sd[SCAN_THREADS];
    const int t = threadIdx.x;
    const int lo = t * SCAN_CHUNK;
    const int hi = min(lo + SCAN_CHUNK, NNODES);

    int s = 0;
    for (int i = lo; i < hi; ++i) s += counts[i];
    sd[t] = s;
    __syncthreads();
    for (int off = 1; off < SCAN_THREADS; off <<= 1) {
        int v = (t >= off) ? sd[t - off] : 0;
        __syncthreads();
        sd[t] += v;
        __syncthreads();
    }
    int run = (t == 0) ? 0 : sd[t - 1];
    for (int i = lo; i < hi; ++i) {
        int c = counts[i];
        rowptr[i] = run;
        counts[i] = run;          // reuse as cursor
        run += c;
    }
    if (t == SCAN_THREADS - 1) rowptr[NNODES] = sd[SCAN_THREADS - 1];
}

// edgeS[pos] = (src, attr) grouped by dst
__global__ __launch_bounds__(256) void fill_kernel(
    const int* __restrict__ src, const int* __restrict__ dst,
    const float* __restrict__ attr, int* __restrict__ cursor,
    int2* __restrict__ edgeS)
{
    int e = blockIdx.x * 256 + threadIdx.x;
    int d = dst[e];
    int pos = atomicAdd(&cursor[d], 1);
    int2 p;
    p.x = src[e];
    p.y = __float_as_int(attr[e]);
    edgeS[pos] = p;
}

// ---------------------------------------------------------------------------
// agg[v] = sum_{e: dst=v} w_e * h[src_e]; degw[v] = sum w_e
// one wave per node, lane = column; no atomics, agg written exactly once
// ---------------------------------------------------------------------------
__global__ __launch_bounds__(256) void gather_kernel(
    const int* __restrict__ rowptr, const int2* __restrict__ edgeS,
    const float* __restrict__ h, float* __restrict__ agg,
    float* __restrict__ degw)
{
    int gid  = blockIdx.x * 256 + threadIdx.x;
    int v    = gid >> 6;             // 4 nodes per block (100000 % 4 == 0)
    int lane = gid & 63;
    int beg = rowptr[v], end = rowptr[v + 1];

    float acc = 0.f, wsum = 0.f;
#pragma unroll 2
    for (int i = beg; i < end; ++i) {
        int2 p = edgeS[i];
        float w = __int_as_float(p.y);
        wsum += w;
        acc  += w * h[(size_t)p.x * HDIM + lane];
    }
    agg[(size_t)v * HDIM + lane] = acc;
    if (lane == 0) degw[v] = wsum;
}

// ---------------------------------------------------------------------------
// h = relu(agg @ W1 + h @ W3 - deg ⊙ (h @ W2) + deg·b1 + b3)   (in place)
// ---------------------------------------------------------------------------
__global__ __launch_bounds__(256) void dense_kernel(
    const float* __restrict__ hin, const float* __restrict__ agg,
    const float* __restrict__ degw,
    const float* __restrict__ W1, const float* __restrict__ b1,
    const float* __restrict__ W2, const float* __restrict__ W3,
    const float* __restrict__ b3, float* __restrict__ hout)
{
    __shared__ float sW1[HDIM * HDIM], sW2[HDIM * HDIM], sW3[HDIM * HDIM];
    __shared__ float sh[32][HDIM], sg[32][HDIM];
    const int tid = threadIdx.x;

    for (int i = tid; i < HDIM * HDIM; i += 256) {
        sW1[i] = W1[i]; sW2[i] = W2[i]; sW3[i] = W3[i];
    }
    const int row0 = blockIdx.x * 32;
    for (int i = tid; i < 32 * HDIM; i += 256) {
        int r = i >> 6, c = i & 63;
        size_t g = (size_t)(row0 + r) * HDIM + c;
        sh[r][c] = hin[g];
        sg[r][c] = agg[g];
    }
    __syncthreads();

    const int j  = tid & 63;
    const int rg = tid >> 6;
    float t1[8], t2[8], t3[8];
#pragma unroll
    for (int r = 0; r < 8; ++r) { t1[r] = 0.f; t2[r] = 0.f; t3[r] = 0.f; }

    for (int k = 0; k < HDIM; ++k) {
        float w1 = sW1[k * HDIM + j];
        float w2 = sW2[k * HDIM + j];
        float w3 = sW3[k * HDIM + j];
#pragma unroll
        for (int r = 0; r < 8; ++r) {
            float hv = sh[rg * 8 + r][k];
            float gv = sg[rg * 8 + r][k];
            t1[r] += gv * w1;
            t2[r] += hv * w2;
            t3[r] += hv * w3;
        }
    }

    const float b1j = b1[j], b3j = b3[j];
#pragma unroll
    for (int r = 0; r < 8; ++r) {
        int row = row0 + rg * 8 + r;
        float deg = degw[row];
        float o = t1[r] + t3[r] - deg * t2[r] + deg * b1j + b3j;
        hout[(size_t)row * HDIM + j] = fmaxf(o, 0.f);
    }
}

// ---------------------------------------------------------------------------
extern "C" void kernel_launch(void* const* d_in, const int* in_sizes, int n_in,
                              void* d_out, int out_size, void* d_ws, size_t ws_size,
                              hipStream_t stream)
{
    const float* x    = (const float*)d_in[0];
    const int*   eidx = (const int*)  d_in[1];   // (2, E) as int32
    const float* attr = (const float*)d_in[2];
    // d_in[3] = batch (unused)
    const float* Wemb = (const float*)d_in[4];
    const float* bemb = (const float*)d_in[5];
    const float* W1   = (const float*)d_in[6];
    const float* b1   = (const float*)d_in[7];
    const float* W2   = (const float*)d_in[8];
    const float* W3   = (const float*)d_in[9];
    const float* b3   = (const float*)d_in[10];

    float* h = (float*)d_out;                    // N x 64, updated in place

    // workspace layout (4-byte units; edgeS placed at 8B-aligned offset)
    float* agg    = (float*)d_ws;                           // N*64
    float* degw   = agg + (size_t)NNODES * HDIM;            // N
    int*   counts = (int*)(degw + NNODES);                  // N (becomes cursor)
    int*   rowptr = counts + NNODES;                        // N+1
    int2*  edgeS  = (int2*)(rowptr + NNODES + 2);           // E pairs (+1 pad for 8B align)

    const int* srcI = eidx;
    const int* dstI = eidx + NEDGES;

    hipMemsetAsync(counts, 0, NNODES * sizeof(int), stream);

    emb_kernel <<<NNODES / 32, 256, 0, stream>>>(x, Wemb, bemb, h);
    hist_kernel<<<NEDGES / 256, 256, 0, stream>>>(dstI, counts);
    scan_kernel<<<1, SCAN_THREADS, 0, stream>>>(counts, rowptr);
    fill_kernel<<<NEDGES / 256, 256, 0, stream>>>(srcI, dstI, attr, counts, edgeS);

    for (int l = 0; l < NLAYERS; ++l) {
        gather_kernel<<<NNODES * HDIM / 256, 256, 0, stream>>>(
            rowptr, edgeS, h, agg, degw);
        dense_kernel<<<NNODES / 32, 256, 0, stream>>>(
            h, agg, degw,
            W1 + (size_t)l * HDIM * HDIM, b1 + (size_t)l * HDIM,
            W2 + (size_t)l * HDIM * HDIM, W3 + (size_t)l * HDIM * HDIM,
            b3 + (size_t)l * HDIM, h);
    }
}

// Round 4
// 586.345 us; speedup vs baseline: 1.7197x; 1.3564x over previous
//
#include <hip/hip_runtime.h>

#define NNODES 100000
#define NEDGES 1600000
#define DINP   128
#define HDIM   64
#define NLAYERS 2
#define SCB 256                       // scan threads/block
#define SCE 1024                      // scan elements/block (4/thread)
#define NSCB ((NNODES + SCE - 1) / SCE)   // 98 blocks

// ---------------------------------------------------------------------------
// h0 = x @ W_emb + b_emb        (N x 128) @ (128 x 64)
// ---------------------------------------------------------------------------
__global__ __launch_bounds__(256) void emb_kernel(
    const float* __restrict__ x, const float* __restrict__ Wemb,
    const float* __restrict__ bemb, float* __restrict__ h)
{
    __shared__ float sW[DINP * HDIM];   // 32 KB
    __shared__ float sx[32][DINP];      // 16 KB
    const int tid = threadIdx.x;

    for (int i = tid; i < DINP * HDIM; i += 256) sW[i] = Wemb[i];

    const int row0 = blockIdx.x * 32;   // 100000 / 32 = 3125
    for (int i = tid; i < 32 * DINP; i += 256) {
        int r = i >> 7, c = i & 127;
        sx[r][c] = x[(size_t)(row0 + r) * DINP + c];
    }
    __syncthreads();

    const int j  = tid & 63;
    const int rg = tid >> 6;
    float acc[8];
    const float bj = bemb[j];
#pragma unroll
    for (int r = 0; r < 8; ++r) acc[r] = bj;

    for (int k = 0; k < DINP; ++k) {
        float w = sW[k * HDIM + j];
#pragma unroll
        for (int r = 0; r < 8; ++r)
            acc[r] += sx[rg * 8 + r][k] * w;
    }
#pragma unroll
    for (int r = 0; r < 8; ++r)
        h[(size_t)(row0 + rg * 8 + r) * HDIM + j] = acc[r];
}

// ---------------------------------------------------------------------------
// CSR build: histogram -> 3-pass scan -> fill
// ---------------------------------------------------------------------------
__global__ __launch_bounds__(256) void hist_kernel(
    const int* __restrict__ dst, int* __restrict__ counts)
{
    int e = blockIdx.x * 256 + threadIdx.x;   // E % 256 == 0
    atomicAdd(&counts[dst[e]], 1);
}

// pass 1: per-block sums of counts (SCE elems / block)
__global__ __launch_bounds__(SCB) void scan_blocksums(
    const int* __restrict__ counts, int* __restrict__ blockSums)
{
    __shared__ int sd[SCB];
    const int b = blockIdx.x, t = threadIdx.x;
    const int base = b * SCE + t * 4;
    int s = 0;
    if (base + 3 < NNODES) {
        int4 v = *(const int4*)(counts + base);
        s = v.x + v.y + v.z + v.w;
    } else {
        for (int k = 0; k < 4; ++k)
            if (base + k < NNODES) s += counts[base + k];
    }
    sd[t] = s;
    __syncthreads();
    for (int off = SCB / 2; off > 0; off >>= 1) {
        if (t < off) sd[t] += sd[t + off];
        __syncthreads();
    }
    if (t == 0) blockSums[b] = sd[0];
}

// pass 2: one block scans the block sums; writes rowptr[N] = total
__global__ __launch_bounds__(128) void scan_offsets(
    const int* __restrict__ blockSums, int* __restrict__ blockOff,
    int* __restrict__ rowptr)
{
    __shared__ int sd[128];
    const int t = threadIdx.x;
    int v = (t < NSCB) ? blockSums[t] : 0;
    sd[t] = v;
    __syncthreads();
    for (int off = 1; off < 128; off <<= 1) {
        int u = (t >= off) ? sd[t - off] : 0;
        __syncthreads();
        sd[t] += u;
        __syncthreads();
    }
    if (t < NSCB) blockOff[t] = sd[t] - v;     // exclusive
    if (t == 127) rowptr[NNODES] = sd[127];    // grand total (= NEDGES)
}

// pass 3: per-block exclusive scan + offset; writes rowptr and cursor
// (cursor aliases counts: each element read-then-written by its own thread)
__global__ __launch_bounds__(SCB) void scan_apply(
    int* __restrict__ counts, const int* __restrict__ blockOff,
    int* __restrict__ rowptr)
{
    __shared__ int sd[SCB];
    const int b = blockIdx.x, t = threadIdx.x;
    const int base = b * SCE + t * 4;
    int c0 = 0, c1 = 0, c2 = 0, c3 = 0;
    if (base + 3 < NNODES) {
        int4 v = *(const int4*)(counts + base);
        c0 = v.x; c1 = v.y; c2 = v.z; c3 = v.w;
    } else {
        if (base + 0 < NNODES) c0 = counts[base + 0];
        if (base + 1 < NNODES) c1 = counts[base + 1];
        if (base + 2 < NNODES) c2 = counts[base + 2];
    }
    const int s = c0 + c1 + c2 + c3;
    sd[t] = s;
    __syncthreads();
    for (int off = 1; off < SCB; off <<= 1) {
        int u = (t >= off) ? sd[t - off] : 0;
        __syncthreads();
        sd[t] += u;
        __syncthreads();
    }
    int run = blockOff[b] + sd[t] - s;   // exclusive prefix for this thread
    int i0 = base;
    if (i0 + 0 < NNODES) { rowptr[i0 + 0] = run; counts[i0 + 0] = run; } run += c0;
    if (i0 + 1 < NNODES) { rowptr[i0 + 1] = run; counts[i0 + 1] = run; } run += c1;
    if (i0 + 2 < NNODES) { rowptr[i0 + 2] = run; counts[i0 + 2] = run; } run += c2;
    if (i0 + 3 < NNODES) { rowptr[i0 + 3] = run; counts[i0 + 3] = run; }
}

// edgeS[pos] = (src, attr) grouped by dst
__global__ __launch_bounds__(256) void fill_kernel(
    const int* __restrict__ src, const int* __restrict__ dst,
    const float* __restrict__ attr, int* __restrict__ cursor,
    int2* __restrict__ edgeS)
{
    int e = blockIdx.x * 256 + threadIdx.x;
    int d = dst[e];
    int pos = atomicAdd(&cursor[d], 1);
    int2 p;
    p.x = src[e];
    p.y = __float_as_int(attr[e]);
    edgeS[pos] = p;
}

// ---------------------------------------------------------------------------
// agg[v] = sum_{e: dst=v} w_e * h[src_e]; degw[v] = sum w_e
// one wave per node, lane = column; no atomics
// ---------------------------------------------------------------------------
__global__ __launch_bounds__(256) void gather_kernel(
    const int* __restrict__ rowptr, const int2* __restrict__ edgeS,
    const float* __restrict__ h, float* __restrict__ agg,
    float* __restrict__ degw)
{
    int gid  = blockIdx.x * 256 + threadIdx.x;
    int v    = gid >> 6;             // 4 nodes per block
    int lane = gid & 63;
    int beg = rowptr[v], end = rowptr[v + 1];

    float acc = 0.f, wsum = 0.f;
#pragma unroll 2
    for (int i = beg; i < end; ++i) {
        int2 p = edgeS[i];
        float w = __int_as_float(p.y);
        wsum += w;
        acc  += w * h[(size_t)p.x * HDIM + lane];
    }
    agg[(size_t)v * HDIM + lane] = acc;
    if (lane == 0) degw[v] = wsum;
}

// ---------------------------------------------------------------------------
// h = relu(agg @ W1 + h @ W3 - deg ⊙ (h @ W2) + deg·b1 + b3)   (in place)
// ---------------------------------------------------------------------------
__global__ __launch_bounds__(256) void dense_kernel(
    const float* __restrict__ hin, const float* __restrict__ agg,
    const float* __restrict__ degw,
    const float* __restrict__ W1, const float* __restrict__ b1,
    const float* __restrict__ W2, const float* __restrict__ W3,
    const float* __restrict__ b3, float* __restrict__ hout)
{
    __shared__ float sW1[HDIM * HDIM], sW2[HDIM * HDIM], sW3[HDIM * HDIM];
    __shared__ float sh[32][HDIM], sg[32][HDIM];
    const int tid = threadIdx.x;

    for (int i = tid; i < HDIM * HDIM; i += 256) {
        sW1[i] = W1[i]; sW2[i] = W2[i]; sW3[i] = W3[i];
    }
    const int row0 = blockIdx.x * 32;
    for (int i = tid; i < 32 * HDIM; i += 256) {
        int r = i >> 6, c = i & 63;
        size_t g = (size_t)(row0 + r) * HDIM + c;
        sh[r][c] = hin[g];
        sg[r][c] = agg[g];
    }
    __syncthreads();

    const int j  = tid & 63;
    const int rg = tid >> 6;
    float t1[8], t2[8], t3[8];
#pragma unroll
    for (int r = 0; r < 8; ++r) { t1[r] = 0.f; t2[r] = 0.f; t3[r] = 0.f; }

    for (int k = 0; k < HDIM; ++k) {
        float w1 = sW1[k * HDIM + j];
        float w2 = sW2[k * HDIM + j];
        float w3 = sW3[k * HDIM + j];
#pragma unroll
        for (int r = 0; r < 8; ++r) {
            float hv = sh[rg * 8 + r][k];
            float gv = sg[rg * 8 + r][k];
            t1[r] += gv * w1;
            t2[r] += hv * w2;
            t3[r] += hv * w3;
        }
    }

    const float b1j = b1[j], b3j = b3[j];
#pragma unroll
    for (int r = 0; r < 8; ++r) {
        int row = row0 + rg * 8 + r;
        float deg = degw[row];
        float o = t1[r] + t3[r] - deg * t2[r] + deg * b1j + b3j;
        hout[(size_t)row * HDIM + j] = fmaxf(o, 0.f);
    }
}

// ---------------------------------------------------------------------------
extern "C" void kernel_launch(void* const* d_in, const int* in_sizes, int n_in,
                              void* d_out, int out_size, void* d_ws, size_t ws_size,
                              hipStream_t stream)
{
    const float* x    = (const float*)d_in[0];
    const int*   eidx = (const int*)  d_in[1];   // (2, E) as int32
    const float* attr = (const float*)d_in[2];
    // d_in[3] = batch (unused)
    const float* Wemb = (const float*)d_in[4];
    const float* bemb = (const float*)d_in[5];
    const float* W1   = (const float*)d_in[6];
    const float* b1   = (const float*)d_in[7];
    const float* W2   = (const float*)d_in[8];
    const float* W3   = (const float*)d_in[9];
    const float* b3   = (const float*)d_in[10];

    float* h = (float*)d_out;                    // N x 64, updated in place

    // workspace layout (4-byte units; int4 loads need 16B alignment: all
    // section offsets below are multiples of 16B given NNODES % 4 == 0)
    float* agg       = (float*)d_ws;                       // N*64
    float* degw      = agg + (size_t)NNODES * HDIM;        // N
    int*   counts    = (int*)(degw + NNODES);              // N (becomes cursor)
    int*   rowptr    = counts + NNODES;                    // N+1
    int*   blockSums = rowptr + NNODES + 3;                // NSCB  (16B-aligned)
    int*   blockOff  = blockSums + NSCB;                   // NSCB
    int2*  edgeS     = (int2*)(blockOff + NSCB + 2);       // E pairs, 8B-aligned

    const int* srcI = eidx;
    const int* dstI = eidx + NEDGES;

    hipMemsetAsync(counts, 0, NNODES * sizeof(int), stream);

    emb_kernel    <<<NNODES / 32, 256, 0, stream>>>(x, Wemb, bemb, h);
    hist_kernel   <<<NEDGES / 256, 256, 0, stream>>>(dstI, counts);
    scan_blocksums<<<NSCB, SCB, 0, stream>>>(counts, blockSums);
    scan_offsets  <<<1, 128, 0, stream>>>(blockSums, blockOff, rowptr);
    scan_apply    <<<NSCB, SCB, 0, stream>>>(counts, blockOff, rowptr);
    fill_kernel   <<<NEDGES / 256, 256, 0, stream>>>(srcI, dstI, attr, counts, edgeS);

    for (int l = 0; l < NLAYERS; ++l) {
        gather_kernel<<<NNODES * HDIM / 256, 256, 0, stream>>>(
            rowptr, edgeS, h, agg, degw);
        dense_kernel<<<NNODES / 32, 256, 0, stream>>>(
            h, agg, degw,
            W1 + (size_t)l * HDIM * HDIM, b1 + (size_t)l * HDIM,
            W2 + (size_t)l * HDIM * HDIM, W3 + (size_t)l * HDIM * HDIM,
            b3 + (size_t)l * HDIM, h);
    }
}

// Round 5
// 437.442 us; speedup vs baseline: 2.3050x; 1.3404x over previous
//
#include <hip/hip_runtime.h>

#define NNODES 100000
#define NEDGES 1600000
#define DINP   128
#define HDIM   64
#define NLAYERS 2

#define NBUCK 256
#define BDIV  391                              // nodes/bucket; 99999/391 = 255
#define TILE  8192
#define NT    ((NEDGES + TILE - 1) / TILE)     // 196 tiles
#define NTOT  (NBUCK * NT)                     // 50176
#define SEG   (NTOT / 1024)                    // 49 per scan thread (exact)

// ---------------------------------------------------------------------------
// h0 = x @ W_emb + b_emb   — float4 LDS broadcasts, k unrolled by 4
// ---------------------------------------------------------------------------
__global__ __launch_bounds__(256) void emb_kernel(
    const float* __restrict__ x, const float* __restrict__ Wemb,
    const float* __restrict__ bemb, float* __restrict__ h)
{
    __shared__ float sW[DINP * HDIM];   // [k][j], 32 KB
    __shared__ float sx[32][DINP];      // 16 KB
    const int tid = threadIdx.x;
    const int row0 = blockIdx.x * 32;   // 100000 / 32 = 3125

    for (int i = tid; i < DINP * HDIM / 4; i += 256)
        ((float4*)sW)[i] = ((const float4*)Wemb)[i];
    for (int i = tid; i < 32 * DINP / 4; i += 256)
        ((float4*)sx)[i] = ((const float4*)(x + (size_t)row0 * DINP))[i];
    __syncthreads();

    const int j  = tid & 63;
    const int rg = tid >> 6;
    float acc[8];
    const float bj = bemb[j];
#pragma unroll
    for (int r = 0; r < 8; ++r) acc[r] = bj;

    const float4* sx4 = (const float4*)sx;      // row stride 32 float4s
    for (int k4 = 0; k4 < DINP / 4; ++k4) {
        const int kb = k4 * 4;
        float w0 = sW[(kb + 0) * HDIM + j];
        float w1 = sW[(kb + 1) * HDIM + j];
        float w2 = sW[(kb + 2) * HDIM + j];
        float w3 = sW[(kb + 3) * HDIM + j];
#pragma unroll
        for (int r = 0; r < 8; ++r) {
            float4 xv = sx4[(rg * 8 + r) * (DINP / 4) + k4];
            acc[r] += xv.x * w0 + xv.y * w1 + xv.z * w2 + xv.w * w3;
        }
    }
#pragma unroll
    for (int r = 0; r < 8; ++r)
        h[(size_t)(row0 + rg * 8 + r) * HDIM + j] = acc[r];
}

// ---------------------------------------------------------------------------
// CSR build, bucketed:
//  p1: per-(tile,bucket) histogram      p2: scan (bucket-major) -> offsets
//  p3: bin edges into tmp (packed key)  p4: per-bucket sort -> edgeS + rowptr
// ---------------------------------------------------------------------------
__global__ __launch_bounds__(256) void p1_hist(
    const int* __restrict__ dst, int* __restrict__ tileOff)
{
    __shared__ int hist[NBUCK];
    const int tl = blockIdx.x, t = threadIdx.x;
    hist[t] = 0;
    __syncthreads();
    const int base = tl * TILE;
#pragma unroll
    for (int i = 0; i < TILE / 256; ++i) {
        int e = base + i * 256 + t;
        if (e < NEDGES) atomicAdd(&hist[dst[e] / BDIV], 1);
    }
    __syncthreads();
    tileOff[t * NT + tl] = hist[t];     // bucket-major
}

// single-block exclusive scan over NTOT ints, in place
__global__ __launch_bounds__(1024) void p2_scan(int* __restrict__ tileOff)
{
    __shared__ int sd[1024];
    const int t = threadIdx.x;
    const int lo = t * SEG;
    int s = 0;
    for (int i = 0; i < SEG; ++i) s += tileOff[lo + i];
    sd[t] = s;
    __syncthreads();
    for (int off = 1; off < 1024; off <<= 1) {
        int v = (t >= off) ? sd[t - off] : 0;
        __syncthreads();
        sd[t] += v;
        __syncthreads();
    }
    int run = sd[t] - s;                // exclusive block prefix
    for (int i = 0; i < SEG; ++i) {
        int c = tileOff[lo + i];
        tileOff[lo + i] = run;
        run += c;
    }
}

// bin edges into tmp: key = (localdst << 17) | src, payload attr
__global__ __launch_bounds__(256) void p3_bin(
    const int* __restrict__ src, const int* __restrict__ dst,
    const float* __restrict__ attr, const int* __restrict__ tileOff,
    int2* __restrict__ tmp)
{
    __shared__ int cur[NBUCK];
    const int tl = blockIdx.x, t = threadIdx.x;
    cur[t] = tileOff[t * NT + tl];
    __syncthreads();
#pragma unroll
    for (int i = 0; i < TILE / 256; ++i) {
        int e = tl * TILE + i * 256 + t;
        if (e < NEDGES) {
            int d  = dst[e];
            int bk = d / BDIV;
            int ld = d - bk * BDIV;
            int pos = atomicAdd(&cur[bk], 1);
            int2 p;
            p.x = (ld << 17) | src[e];
            p.y = __float_as_int(attr[e]);
            tmp[pos] = p;
        }
    }
}

// per-bucket: local node hist + scan -> rowptr; scatter tmp -> edgeS
__global__ __launch_bounds__(256) void p4_sort(
    const int2* __restrict__ tmp, const int* __restrict__ tileOff,
    int2* __restrict__ edgeS, int* __restrict__ rowptr)
{
    __shared__ int sdh[512];            // padded hist/scan
    __shared__ int cur[BDIV + 1];
    const int b = blockIdx.x, t = threadIdx.x;
    const int n0 = b * BDIV;
    const int nn = (NNODES - n0 < BDIV) ? (NNODES - n0) : BDIV;
    const int ebeg = tileOff[b * NT];
    const int eend = (b + 1 < NBUCK) ? tileOff[(b + 1) * NT] : NEDGES;

    sdh[t] = 0; sdh[t + 256] = 0;
    __syncthreads();
    for (int e = ebeg + t; e < eend; e += 256)
        atomicAdd(&sdh[tmp[e].x >> 17], 1);
    __syncthreads();
    // inclusive Hillis-Steele over 512 (2 elems/thread)
    for (int off = 1; off < 512; off <<= 1) {
        int i0 = t, i1 = t + 256;
        int v0 = (i0 >= off) ? sdh[i0 - off] : 0;
        int v1 = (i1 >= off) ? sdh[i1 - off] : 0;
        __syncthreads();
        sdh[i0] += v0; sdh[i1] += v1;
        __syncthreads();
    }
    // exclusive cursors + rowptr
    for (int i = t; i < nn; i += 256) {
        int c = ebeg + (i ? sdh[i - 1] : 0);
        cur[i] = c;
        rowptr[n0 + i] = c;
    }
    if (b == NBUCK - 1 && t == 0) rowptr[NNODES] = NEDGES;
    __syncthreads();
    for (int e = ebeg + t; e < eend; e += 256) {
        int2 w = tmp[e];
        int ld = w.x >> 17;
        int pos = atomicAdd(&cur[ld], 1);
        int2 p;
        p.x = w.x & 0x1FFFF;
        p.y = w.y;
        edgeS[pos] = p;
    }
}

// ---------------------------------------------------------------------------
// agg[v] = sum_{e: dst=v} w_e * h[src_e]; degw[v] = sum w_e
// ---------------------------------------------------------------------------
__global__ __launch_bounds__(256) void gather_kernel(
    const int* __restrict__ rowptr, const int2* __restrict__ edgeS,
    const float* __restrict__ h, float* __restrict__ agg,
    float* __restrict__ degw)
{
    int gid  = blockIdx.x * 256 + threadIdx.x;
    int v    = gid >> 6;
    int lane = gid & 63;
    int beg = rowptr[v], end = rowptr[v + 1];

    float acc = 0.f, wsum = 0.f;
#pragma unroll 2
    for (int i = beg; i < end; ++i) {
        int2 p = edgeS[i];
        float w = __int_as_float(p.y);
        wsum += w;
        acc  += w * h[(size_t)p.x * HDIM + lane];
    }
    agg[(size_t)v * HDIM + lane] = acc;
    if (lane == 0) degw[v] = wsum;
}

// ---------------------------------------------------------------------------
// h = relu(agg @ W1 + h @ W3 - deg ⊙ (h @ W2) + deg·b1 + b3)   (in place)
// float4 LDS broadcasts for values, k unrolled by 4
// ---------------------------------------------------------------------------
__global__ __launch_bounds__(256) void dense_kernel(
    const float* __restrict__ hin, const float* __restrict__ agg,
    const float* __restrict__ degw,
    const float* __restrict__ W1, const float* __restrict__ b1,
    const float* __restrict__ W2, const float* __restrict__ W3,
    const float* __restrict__ b3, float* __restrict__ hout)
{
    __shared__ float sW1[HDIM * HDIM], sW2[HDIM * HDIM], sW3[HDIM * HDIM];
    __shared__ float sh[32][HDIM], sg[32][HDIM];
    const int tid = threadIdx.x;
    const int row0 = blockIdx.x * 32;

    for (int i = tid; i < HDIM * HDIM / 4; i += 256) {
        ((float4*)sW1)[i] = ((const float4*)W1)[i];
        ((float4*)sW2)[i] = ((const float4*)W2)[i];
        ((float4*)sW3)[i] = ((const float4*)W3)[i];
    }
    for (int i = tid; i < 32 * HDIM / 4; i += 256) {
        ((float4*)sh)[i] = ((const float4*)(hin + (size_t)row0 * HDIM))[i];
        ((float4*)sg)[i] = ((const float4*)(agg + (size_t)row0 * HDIM))[i];
    }
    __syncthreads();

    const int j  = tid & 63;
    const int rg = tid >> 6;
    float t1[8], t2[8], t3[8];
#pragma unroll
    for (int r = 0; r < 8; ++r) { t1[r] = 0.f; t2[r] = 0.f; t3[r] = 0.f; }

    const float4* sh4 = (const float4*)sh;   // row stride 16 float4s
    const float4* sg4 = (const float4*)sg;
    for (int k4 = 0; k4 < HDIM / 4; ++k4) {
        const int kb = k4 * 4;
        float w1k[4], w2k[4], w3k[4];
#pragma unroll
        for (int kk = 0; kk < 4; ++kk) {
            w1k[kk] = sW1[(kb + kk) * HDIM + j];
            w2k[kk] = sW2[(kb + kk) * HDIM + j];
            w3k[kk] = sW3[(kb + kk) * HDIM + j];
        }
#pragma unroll
        for (int r = 0; r < 8; ++r) {
            float4 gv = sg4[(rg * 8 + r) * (HDIM / 4) + k4];
            float4 hv = sh4[(rg * 8 + r) * (HDIM / 4) + k4];
            t1[r] += gv.x * w1k[0] + gv.y * w1k[1] + gv.z * w1k[2] + gv.w * w1k[3];
            t2[r] += hv.x * w2k[0] + hv.y * w2k[1] + hv.z * w2k[2] + hv.w * w2k[3];
            t3[r] += hv.x * w3k[0] + hv.y * w3k[1] + hv.z * w3k[2] + hv.w * w3k[3];
        }
    }

    const float b1j = b1[j], b3j = b3[j];
#pragma unroll
    for (int r = 0; r < 8; ++r) {
        int row = row0 + rg * 8 + r;
        float deg = degw[row];
        float o = t1[r] + t3[r] - deg * t2[r] + deg * b1j + b3j;
        hout[(size_t)row * HDIM + j] = fmaxf(o, 0.f);
    }
}

// ---------------------------------------------------------------------------
extern "C" void kernel_launch(void* const* d_in, const int* in_sizes, int n_in,
                              void* d_out, int out_size, void* d_ws, size_t ws_size,
                              hipStream_t stream)
{
    const float* x    = (const float*)d_in[0];
    const int*   eidx = (const int*)  d_in[1];   // (2, E) as int32
    const float* attr = (const float*)d_in[2];
    // d_in[3] = batch (unused)
    const float* Wemb = (const float*)d_in[4];
    const float* bemb = (const float*)d_in[5];
    const float* W1   = (const float*)d_in[6];
    const float* b1   = (const float*)d_in[7];
    const float* W2   = (const float*)d_in[8];
    const float* W3   = (const float*)d_in[9];
    const float* b3   = (const float*)d_in[10];

    float* h = (float*)d_out;                    // N x 64, in place

    // workspace: tmp ALIASES agg (disjoint lifetime: CSR build vs layers)
    float* agg     = (float*)d_ws;                       // N*64 floats (25.6 MB)
    int2*  tmp     = (int2*)d_ws;                        // E int2 (12.8 MB) — alias
    float* degw    = agg + (size_t)NNODES * HDIM;        // N
    int*   rowptr  = (int*)(degw + NNODES);              // N+1
    int*   tileOff = rowptr + NNODES + 3;                // NTOT (even offset)
    int2*  edgeS   = (int2*)(tileOff + NTOT + 2);        // E int2 (12.8 MB)

    const int* srcI = eidx;
    const int* dstI = eidx + NEDGES;

    emb_kernel<<<NNODES / 32, 256, 0, stream>>>(x, Wemb, bemb, h);

    p1_hist<<<NT, 256, 0, stream>>>(dstI, tileOff);
    p2_scan<<<1, 1024, 0, stream>>>(tileOff);
    p3_bin <<<NT, 256, 0, stream>>>(srcI, dstI, attr, tileOff, tmp);
    p4_sort<<<NBUCK, 256, 0, stream>>>(tmp, tileOff, edgeS, rowptr);

    for (int l = 0; l < NLAYERS; ++l) {
        gather_kernel<<<NNODES * HDIM / 256, 256, 0, stream>>>(
            rowptr, edgeS, h, agg, degw);
        dense_kernel<<<NNODES / 32, 256, 0, stream>>>(
            h, agg, degw,
            W1 + (size_t)l * HDIM * HDIM, b1 + (size_t)l * HDIM,
            W2 + (size_t)l * HDIM * HDIM, W3 + (size_t)l * HDIM * HDIM,
            b3 + (size_t)l * HDIM, h);
    }
}

// Round 6
// 437.424 us; speedup vs baseline: 2.3051x; 1.0000x over previous
//
#include <hip/hip_runtime.h>

#define NNODES 100000
#define NEDGES 1600000
#define DINP   128
#define HDIM   64
#define NLAYERS 2

#define NBUCK 256
#define BDIV  391                              // nodes/bucket; 99999/391 = 255
#define TILE  8192
#define NT    ((NEDGES + TILE - 1) / TILE)     // 196 tiles
#define NTOT  (NBUCK * NT)                     // 50176
#define SEG   (NTOT / 1024)                    // 49 per scan thread (exact)

typedef unsigned short ushort_t;
typedef unsigned int   uint_t;

__device__ __forceinline__ ushort_t f32_to_bf16_rne(float x) {
    uint_t u = __float_as_uint(x);
    u = (u + 0x7FFFu + ((u >> 16) & 1u)) >> 16;
    return (ushort_t)u;
}
__device__ __forceinline__ float bf16_to_f32(ushort_t v) {
    return __uint_as_float(((uint_t)v) << 16);
}

// ---------------------------------------------------------------------------
// h0 = x @ W_emb + b_emb   — float4 LDS broadcasts, k unrolled by 4
// writes fp32 h and bf16 shadow hbf
// ---------------------------------------------------------------------------
__global__ __launch_bounds__(256) void emb_kernel(
    const float* __restrict__ x, const float* __restrict__ Wemb,
    const float* __restrict__ bemb, float* __restrict__ h,
    ushort_t* __restrict__ hbf)
{
    __shared__ float sW[DINP * HDIM];   // [k][j], 32 KB
    __shared__ float sx[32][DINP];      // 16 KB
    const int tid = threadIdx.x;
    const int row0 = blockIdx.x * 32;   // 100000 / 32 = 3125

    for (int i = tid; i < DINP * HDIM / 4; i += 256)
        ((float4*)sW)[i] = ((const float4*)Wemb)[i];
    for (int i = tid; i < 32 * DINP / 4; i += 256)
        ((float4*)sx)[i] = ((const float4*)(x + (size_t)row0 * DINP))[i];
    __syncthreads();

    const int j  = tid & 63;
    const int rg = tid >> 6;
    float acc[8];
    const float bj = bemb[j];
#pragma unroll
    for (int r = 0; r < 8; ++r) acc[r] = bj;

    const float4* sx4 = (const float4*)sx;      // row stride DINP/4 float4s
    for (int k4 = 0; k4 < DINP / 4; ++k4) {
        const int kb = k4 * 4;
        float w0 = sW[(kb + 0) * HDIM + j];
        float w1 = sW[(kb + 1) * HDIM + j];
        float w2 = sW[(kb + 2) * HDIM + j];
        float w3 = sW[(kb + 3) * HDIM + j];
#pragma unroll
        for (int r = 0; r < 8; ++r) {
            float4 xv = sx4[(rg * 8 + r) * (DINP / 4) + k4];
            acc[r] += xv.x * w0 + xv.y * w1 + xv.z * w2 + xv.w * w3;
        }
    }
#pragma unroll
    for (int r = 0; r < 8; ++r) {
        size_t g = (size_t)(row0 + rg * 8 + r) * HDIM + j;
        h[g]   = acc[r];
        hbf[g] = f32_to_bf16_rne(acc[r]);
    }
}

// ---------------------------------------------------------------------------
// CSR build, bucketed:
//  p1: per-(tile,bucket) histogram      p2: scan (bucket-major) -> offsets
//  p3: bin edges into tmp (packed key)  p4: per-bucket sort -> edgeS + rowptr
// ---------------------------------------------------------------------------
__global__ __launch_bounds__(256) void p1_hist(
    const int* __restrict__ dst, int* __restrict__ tileOff)
{
    __shared__ int hist[NBUCK];
    const int tl = blockIdx.x, t = threadIdx.x;
    hist[t] = 0;
    __syncthreads();
    const int base = tl * TILE;
#pragma unroll
    for (int i = 0; i < TILE / 256; ++i) {
        int e = base + i * 256 + t;
        if (e < NEDGES) atomicAdd(&hist[dst[e] / BDIV], 1);
    }
    __syncthreads();
    tileOff[t * NT + tl] = hist[t];     // bucket-major
}

// single-block exclusive scan over NTOT ints, in place
__global__ __launch_bounds__(1024) void p2_scan(int* __restrict__ tileOff)
{
    __shared__ int sd[1024];
    const int t = threadIdx.x;
    const int lo = t * SEG;
    int s = 0;
    for (int i = 0; i < SEG; ++i) s += tileOff[lo + i];
    sd[t] = s;
    __syncthreads();
    for (int off = 1; off < 1024; off <<= 1) {
        int v = (t >= off) ? sd[t - off] : 0;
        __syncthreads();
        sd[t] += v;
        __syncthreads();
    }
    int run = sd[t] - s;                // exclusive block prefix
    for (int i = 0; i < SEG; ++i) {
        int c = tileOff[lo + i];
        tileOff[lo + i] = run;
        run += c;
    }
}

// bin edges into tmp: key = (localdst << 17) | src, payload attr
__global__ __launch_bounds__(256) void p3_bin(
    const int* __restrict__ src, const int* __restrict__ dst,
    const float* __restrict__ attr, const int* __restrict__ tileOff,
    int2* __restrict__ tmp)
{
    __shared__ int cur[NBUCK];
    const int tl = blockIdx.x, t = threadIdx.x;
    cur[t] = tileOff[t * NT + tl];
    __syncthreads();
#pragma unroll
    for (int i = 0; i < TILE / 256; ++i) {
        int e = tl * TILE + i * 256 + t;
        if (e < NEDGES) {
            int d  = dst[e];
            int bk = d / BDIV;
            int ld = d - bk * BDIV;
            int pos = atomicAdd(&cur[bk], 1);
            int2 p;
            p.x = (ld << 17) | src[e];
            p.y = __float_as_int(attr[e]);
            tmp[pos] = p;
        }
    }
}

// per-bucket: local node hist + scan -> rowptr; scatter tmp -> edgeS
__global__ __launch_bounds__(256) void p4_sort(
    const int2* __restrict__ tmp, const int* __restrict__ tileOff,
    int2* __restrict__ edgeS, int* __restrict__ rowptr)
{
    __shared__ int sdh[512];            // padded hist/scan
    __shared__ int cur[BDIV + 1];
    const int b = blockIdx.x, t = threadIdx.x;
    const int n0 = b * BDIV;
    const int nn = (NNODES - n0 < BDIV) ? (NNODES - n0) : BDIV;
    const int ebeg = tileOff[b * NT];
    const int eend = (b + 1 < NBUCK) ? tileOff[(b + 1) * NT] : NEDGES;

    sdh[t] = 0; sdh[t + 256] = 0;
    __syncthreads();
    for (int e = ebeg + t; e < eend; e += 256)
        atomicAdd(&sdh[tmp[e].x >> 17], 1);
    __syncthreads();
    for (int off = 1; off < 512; off <<= 1) {
        int i0 = t, i1 = t + 256;
        int v0 = (i0 >= off) ? sdh[i0 - off] : 0;
        int v1 = (i1 >= off) ? sdh[i1 - off] : 0;
        __syncthreads();
        sdh[i0] += v0; sdh[i1] += v1;
        __syncthreads();
    }
    for (int i = t; i < nn; i += 256) {
        int c = ebeg + (i ? sdh[i - 1] : 0);
        cur[i] = c;
        rowptr[n0 + i] = c;
    }
    if (b == NBUCK - 1 && t == 0) rowptr[NNODES] = NEDGES;
    __syncthreads();
    for (int e = ebeg + t; e < eend; e += 256) {
        int2 w = tmp[e];
        int ld = w.x >> 17;
        int pos = atomicAdd(&cur[ld], 1);
        int2 p;
        p.x = w.x & 0x1FFFF;
        p.y = w.y;
        edgeS[pos] = p;
    }
}

// ---------------------------------------------------------------------------
// agg[v] = sum_{e: dst=v} w_e * hbf[src_e]; degw[v] = sum w_e
// bf16 gather: 128 B/row instead of 256 B
// ---------------------------------------------------------------------------
__global__ __launch_bounds__(256) void gather_kernel(
    const int* __restrict__ rowptr, const int2* __restrict__ edgeS,
    const ushort_t* __restrict__ hbf, float* __restrict__ agg,
    float* __restrict__ degw)
{
    int gid  = blockIdx.x * 256 + threadIdx.x;
    int v    = gid >> 6;
    int lane = gid & 63;
    int beg = rowptr[v], end = rowptr[v + 1];

    float acc = 0.f, wsum = 0.f;
#pragma unroll 2
    for (int i = beg; i < end; ++i) {
        int2 p = edgeS[i];
        float w = __int_as_float(p.y);
        wsum += w;
        acc  += w * bf16_to_f32(hbf[(size_t)p.x * HDIM + lane]);
    }
    agg[(size_t)v * HDIM + lane] = acc;
    if (lane == 0) degw[v] = wsum;
}

// ---------------------------------------------------------------------------
// h = relu(agg @ W1 + h @ W3 - deg ⊙ (h @ W2) + deg·b1 + b3)   (in place)
// writes fp32 h and bf16 shadow hbf
// ---------------------------------------------------------------------------
__global__ __launch_bounds__(256) void dense_kernel(
    const float* __restrict__ hin, const float* __restrict__ agg,
    const float* __restrict__ degw,
    const float* __restrict__ W1, const float* __restrict__ b1,
    const float* __restrict__ W2, const float* __restrict__ W3,
    const float* __restrict__ b3, float* __restrict__ hout,
    ushort_t* __restrict__ hbf)
{
    __shared__ float sW1[HDIM * HDIM], sW2[HDIM * HDIM], sW3[HDIM * HDIM];
    __shared__ float sh[32][HDIM], sg[32][HDIM];
    const int tid = threadIdx.x;
    const int row0 = blockIdx.x * 32;

    for (int i = tid; i < HDIM * HDIM / 4; i += 256) {
        ((float4*)sW1)[i] = ((const float4*)W1)[i];
        ((float4*)sW2)[i] = ((const float4*)W2)[i];
        ((float4*)sW3)[i] = ((const float4*)W3)[i];
    }
    for (int i = tid; i < 32 * HDIM / 4; i += 256) {
        ((float4*)sh)[i] = ((const float4*)(hin + (size_t)row0 * HDIM))[i];
        ((float4*)sg)[i] = ((const float4*)(agg + (size_t)row0 * HDIM))[i];
    }
    __syncthreads();

    const int j  = tid & 63;
    const int rg = tid >> 6;
    float t1[8], t2[8], t3[8];
#pragma unroll
    for (int r = 0; r < 8; ++r) { t1[r] = 0.f; t2[r] = 0.f; t3[r] = 0.f; }

    const float4* sh4 = (const float4*)sh;   // row stride HDIM/4 float4s
    const float4* sg4 = (const float4*)sg;
    for (int k4 = 0; k4 < HDIM / 4; ++k4) {
        const int kb = k4 * 4;
        float w1k[4], w2k[4], w3k[4];
#pragma unroll
        for (int kk = 0; kk < 4; ++kk) {
            w1k[kk] = sW1[(kb + kk) * HDIM + j];
            w2k[kk] = sW2[(kb + kk) * HDIM + j];
            w3k[kk] = sW3[(kb + kk) * HDIM + j];
        }
#pragma unroll
        for (int r = 0; r < 8; ++r) {
            float4 gv = sg4[(rg * 8 + r) * (HDIM / 4) + k4];
            float4 hv = sh4[(rg * 8 + r) * (HDIM / 4) + k4];
            t1[r] += gv.x * w1k[0] + gv.y * w1k[1] + gv.z * w1k[2] + gv.w * w1k[3];
            t2[r] += hv.x * w2k[0] + hv.y * w2k[1] + hv.z * w2k[2] + hv.w * w2k[3];
            t3[r] += hv.x * w3k[0] + hv.y * w3k[1] + hv.z * w3k[2] + hv.w * w3k[3];
        }
    }

    const float b1j = b1[j], b3j = b3[j];
#pragma unroll
    for (int r = 0; r < 8; ++r) {
        int row = row0 + rg * 8 + r;
        float deg = degw[row];
        float o = t1[r] + t3[r] - deg * t2[r] + deg * b1j + b3j;
        o = fmaxf(o, 0.f);
        size_t g = (size_t)row * HDIM + j;
        hout[g] = o;
        hbf[g]  = f32_to_bf16_rne(o);
    }
}

// ---------------------------------------------------------------------------
extern "C" void kernel_launch(void* const* d_in, const int* in_sizes, int n_in,
                              void* d_out, int out_size, void* d_ws, size_t ws_size,
                              hipStream_t stream)
{
    const float* x    = (const float*)d_in[0];
    const int*   eidx = (const int*)  d_in[1];   // (2, E) as int32
    const float* attr = (const float*)d_in[2];
    // d_in[3] = batch (unused)
    const float* Wemb = (const float*)d_in[4];
    const float* bemb = (const float*)d_in[5];
    const float* W1   = (const float*)d_in[6];
    const float* b1   = (const float*)d_in[7];
    const float* W2   = (const float*)d_in[8];
    const float* W3   = (const float*)d_in[9];
    const float* b3   = (const float*)d_in[10];

    float* h = (float*)d_out;                    // N x 64, in place

    // workspace: tmp ALIASES agg (disjoint lifetime: CSR build vs layers)
    float*    agg     = (float*)d_ws;                      // N*64 f32 (25.6 MB)
    int2*     tmp     = (int2*)d_ws;                       // E int2 (12.8 MB) — alias
    float*    degw    = agg + (size_t)NNODES * HDIM;       // N
    int*      rowptr  = (int*)(degw + NNODES);             // N+1
    int*      tileOff = rowptr + NNODES + 3;               // NTOT
    int2*     edgeS   = (int2*)(tileOff + NTOT + 2);       // E int2 (12.8 MB)
    ushort_t* hbf     = (ushort_t*)(edgeS + NEDGES);       // N*64 bf16 (12.8 MB)

    const int* srcI = eidx;
    const int* dstI = eidx + NEDGES;

    emb_kernel<<<NNODES / 32, 256, 0, stream>>>(x, Wemb, bemb, h, hbf);

    p1_hist<<<NT, 256, 0, stream>>>(dstI, tileOff);
    p2_scan<<<1, 1024, 0, stream>>>(tileOff);
    p3_bin <<<NT, 256, 0, stream>>>(srcI, dstI, attr, tileOff, tmp);
    p4_sort<<<NBUCK, 256, 0, stream>>>(tmp, tileOff, edgeS, rowptr);

    for (int l = 0; l < NLAYERS; ++l) {
        gather_kernel<<<NNODES * HDIM / 256, 256, 0, stream>>>(
            rowptr, edgeS, hbf, agg, degw);
        dense_kernel<<<NNODES / 32, 256, 0, stream>>>(
            h, agg, degw,
            W1 + (size_t)l * HDIM * HDIM, b1 + (size_t)l * HDIM,
            W2 + (size_t)l * HDIM * HDIM, W3 + (size_t)l * HDIM * HDIM,
            b3 + (size_t)l * HDIM, h, hbf);
    }
}

// Round 7
// 406.811 us; speedup vs baseline: 2.4786x; 1.0753x over previous
//
#include <hip/hip_runtime.h>

#define NNODES 100000
#define NEDGES 1600000
#define DINP   128
#define HDIM   64
#define NLAYERS 2

#define NBUCK 256
#define BDIV  391                              // nodes/bucket; 99999/391 = 255
#define TILE  8192
#define NT    ((NEDGES + TILE - 1) / TILE)     // 196 tiles
#define NTOT  (NBUCK * NT)                     // 50176
#define SEG   (NTOT / 1024)                    // 49 per scan thread (exact)

typedef unsigned short ushort_t;
typedef unsigned int   uint_t;

__device__ __forceinline__ ushort_t f32_to_bf16_rne(float x) {
    uint_t u = __float_as_uint(x);
    u = (u + 0x7FFFu + ((u >> 16) & 1u)) >> 16;
    return (ushort_t)u;
}
__device__ __forceinline__ float bf16_to_f32(ushort_t v) {
    return __uint_as_float(((uint_t)v) << 16);
}

// ---------------------------------------------------------------------------
// h0 = x @ W_emb + b_emb   — float4 LDS broadcasts, k unrolled by 4
// writes fp32 h and bf16 shadow hbf
// ---------------------------------------------------------------------------
__global__ __launch_bounds__(256) void emb_kernel(
    const float* __restrict__ x, const float* __restrict__ Wemb,
    const float* __restrict__ bemb, float* __restrict__ h,
    ushort_t* __restrict__ hbf)
{
    __shared__ float sW[DINP * HDIM];   // [k][j], 32 KB
    __shared__ float sx[32][DINP];      // 16 KB
    const int tid = threadIdx.x;
    const int row0 = blockIdx.x * 32;   // 100000 / 32 = 3125

    for (int i = tid; i < DINP * HDIM / 4; i += 256)
        ((float4*)sW)[i] = ((const float4*)Wemb)[i];
    for (int i = tid; i < 32 * DINP / 4; i += 256)
        ((float4*)sx)[i] = ((const float4*)(x + (size_t)row0 * DINP))[i];
    __syncthreads();

    const int j  = tid & 63;
    const int rg = tid >> 6;
    float acc[8];
    const float bj = bemb[j];
#pragma unroll
    for (int r = 0; r < 8; ++r) acc[r] = bj;

    const float4* sx4 = (const float4*)sx;      // row stride DINP/4 float4s
    for (int k4 = 0; k4 < DINP / 4; ++k4) {
        const int kb = k4 * 4;
        float w0 = sW[(kb + 0) * HDIM + j];
        float w1 = sW[(kb + 1) * HDIM + j];
        float w2 = sW[(kb + 2) * HDIM + j];
        float w3 = sW[(kb + 3) * HDIM + j];
#pragma unroll
        for (int r = 0; r < 8; ++r) {
            float4 xv = sx4[(rg * 8 + r) * (DINP / 4) + k4];
            acc[r] += xv.x * w0 + xv.y * w1 + xv.z * w2 + xv.w * w3;
        }
    }
#pragma unroll
    for (int r = 0; r < 8; ++r) {
        size_t g = (size_t)(row0 + rg * 8 + r) * HDIM + j;
        h[g]   = acc[r];
        hbf[g] = f32_to_bf16_rne(acc[r]);
    }
}

// ---------------------------------------------------------------------------
// CSR build, bucketed:
//  p1: per-(tile,bucket) histogram      p2: scan (bucket-major) -> offsets
//  p3: bin edges into tmp (packed key)  p4: per-bucket sort -> edgeS + rowptr
// ---------------------------------------------------------------------------
__global__ __launch_bounds__(256) void p1_hist(
    const int* __restrict__ dst, int* __restrict__ tileOff)
{
    __shared__ int hist[NBUCK];
    const int tl = blockIdx.x, t = threadIdx.x;
    hist[t] = 0;
    __syncthreads();
    const int base = tl * TILE;
#pragma unroll
    for (int i = 0; i < TILE / 256; ++i) {
        int e = base + i * 256 + t;
        if (e < NEDGES) atomicAdd(&hist[dst[e] / BDIV], 1);
    }
    __syncthreads();
    tileOff[t * NT + tl] = hist[t];     // bucket-major
}

// single-block exclusive scan over NTOT ints, in place
__global__ __launch_bounds__(1024) void p2_scan(int* __restrict__ tileOff)
{
    __shared__ int sd[1024];
    const int t = threadIdx.x;
    const int lo = t * SEG;
    int s = 0;
    for (int i = 0; i < SEG; ++i) s += tileOff[lo + i];
    sd[t] = s;
    __syncthreads();
    for (int off = 1; off < 1024; off <<= 1) {
        int v = (t >= off) ? sd[t - off] : 0;
        __syncthreads();
        sd[t] += v;
        __syncthreads();
    }
    int run = sd[t] - s;                // exclusive block prefix
    for (int i = 0; i < SEG; ++i) {
        int c = tileOff[lo + i];
        tileOff[lo + i] = run;
        run += c;
    }
}

// bin edges into tmp: key = (localdst << 17) | src, payload attr
__global__ __launch_bounds__(256) void p3_bin(
    const int* __restrict__ src, const int* __restrict__ dst,
    const float* __restrict__ attr, const int* __restrict__ tileOff,
    int2* __restrict__ tmp)
{
    __shared__ int cur[NBUCK];
    const int tl = blockIdx.x, t = threadIdx.x;
    cur[t] = tileOff[t * NT + tl];
    __syncthreads();
#pragma unroll
    for (int i = 0; i < TILE / 256; ++i) {
        int e = tl * TILE + i * 256 + t;
        if (e < NEDGES) {
            int d  = dst[e];
            int bk = d / BDIV;
            int ld = d - bk * BDIV;
            int pos = atomicAdd(&cur[bk], 1);
            int2 p;
            p.x = (ld << 17) | src[e];
            p.y = __float_as_int(attr[e]);
            tmp[pos] = p;
        }
    }
}

// per-bucket: local node hist + scan -> rowptr; scatter tmp -> edgeS
__global__ __launch_bounds__(256) void p4_sort(
    const int2* __restrict__ tmp, const int* __restrict__ tileOff,
    int2* __restrict__ edgeS, int* __restrict__ rowptr)
{
    __shared__ int sdh[512];            // padded hist/scan
    __shared__ int cur[BDIV + 1];
    const int b = blockIdx.x, t = threadIdx.x;
    const int n0 = b * BDIV;
    const int nn = (NNODES - n0 < BDIV) ? (NNODES - n0) : BDIV;
    const int ebeg = tileOff[b * NT];
    const int eend = (b + 1 < NBUCK) ? tileOff[(b + 1) * NT] : NEDGES;

    sdh[t] = 0; sdh[t + 256] = 0;
    __syncthreads();
    for (int e = ebeg + t; e < eend; e += 256)
        atomicAdd(&sdh[tmp[e].x >> 17], 1);
    __syncthreads();
    for (int off = 1; off < 512; off <<= 1) {
        int i0 = t, i1 = t + 256;
        int v0 = (i0 >= off) ? sdh[i0 - off] : 0;
        int v1 = (i1 >= off) ? sdh[i1 - off] : 0;
        __syncthreads();
        sdh[i0] += v0; sdh[i1] += v1;
        __syncthreads();
    }
    for (int i = t; i < nn; i += 256) {
        int c = ebeg + (i ? sdh[i - 1] : 0);
        cur[i] = c;
        rowptr[n0 + i] = c;
    }
    if (b == NBUCK - 1 && t == 0) rowptr[NNODES] = NEDGES;
    __syncthreads();
    for (int e = ebeg + t; e < eend; e += 256) {
        int2 w = tmp[e];
        int ld = w.x >> 17;
        int pos = atomicAdd(&cur[ld], 1);
        int2 p;
        p.x = w.x & 0x1FFFF;
        p.y = w.y;
        edgeS[pos] = p;
    }
}

// ---------------------------------------------------------------------------
// agg[v] = sum_{e: dst=v} w_e * hbf[src_e]; degw[v] = sum w_e
// unroll-8 batched loads: 8 edge loads || 8 row loads per memory round-trip
// tail handled by clamp-to-beg with zero weight (no serial remainder)
// ---------------------------------------------------------------------------
#define GU 8
__global__ __launch_bounds__(256) void gather_kernel(
    const int* __restrict__ rowptr, const int2* __restrict__ edgeS,
    const ushort_t* __restrict__ hbf, float* __restrict__ agg,
    float* __restrict__ degw)
{
    int gid  = blockIdx.x * 256 + threadIdx.x;
    int v    = gid >> 6;
    int lane = gid & 63;
    int beg = rowptr[v], end = rowptr[v + 1];

    float acc = 0.f, wsum = 0.f;
    for (int i = beg; i < end; i += GU) {
        int   s[GU];
        float w[GU];
        ushort_t hv[GU];
#pragma unroll
        for (int k = 0; k < GU; ++k) {
            bool ok = (i + k < end);
            int2 p = edgeS[ok ? (i + k) : beg];
            s[k] = p.x;
            w[k] = ok ? __int_as_float(p.y) : 0.f;
        }
#pragma unroll
        for (int k = 0; k < GU; ++k)
            hv[k] = hbf[(size_t)s[k] * HDIM + lane];
#pragma unroll
        for (int k = 0; k < GU; ++k) {
            wsum += w[k];
            acc  += w[k] * bf16_to_f32(hv[k]);
        }
    }
    agg[(size_t)v * HDIM + lane] = acc;
    if (lane == 0) degw[v] = wsum;
}

// ---------------------------------------------------------------------------
// h = relu(agg @ W1 + h @ W3 - deg ⊙ (h @ W2) + deg·b1 + b3)   (in place)
// writes fp32 h and bf16 shadow hbf
// ---------------------------------------------------------------------------
__global__ __launch_bounds__(256) void dense_kernel(
    const float* __restrict__ hin, const float* __restrict__ agg,
    const float* __restrict__ degw,
    const float* __restrict__ W1, const float* __restrict__ b1,
    const float* __restrict__ W2, const float* __restrict__ W3,
    const float* __restrict__ b3, float* __restrict__ hout,
    ushort_t* __restrict__ hbf)
{
    __shared__ float sW1[HDIM * HDIM], sW2[HDIM * HDIM], sW3[HDIM * HDIM];
    __shared__ float sh[32][HDIM], sg[32][HDIM];
    const int tid = threadIdx.x;
    const int row0 = blockIdx.x * 32;

    for (int i = tid; i < HDIM * HDIM / 4; i += 256) {
        ((float4*)sW1)[i] = ((const float4*)W1)[i];
        ((float4*)sW2)[i] = ((const float4*)W2)[i];
        ((float4*)sW3)[i] = ((const float4*)W3)[i];
    }
    for (int i = tid; i < 32 * HDIM / 4; i += 256) {
        ((float4*)sh)[i] = ((const float4*)(hin + (size_t)row0 * HDIM))[i];
        ((float4*)sg)[i] = ((const float4*)(agg + (size_t)row0 * HDIM))[i];
    }
    __syncthreads();

    const int j  = tid & 63;
    const int rg = tid >> 6;
    float t1[8], t2[8], t3[8];
#pragma unroll
    for (int r = 0; r < 8; ++r) { t1[r] = 0.f; t2[r] = 0.f; t3[r] = 0.f; }

    const float4* sh4 = (const float4*)sh;   // row stride HDIM/4 float4s
    const float4* sg4 = (const float4*)sg;
    for (int k4 = 0; k4 < HDIM / 4; ++k4) {
        const int kb = k4 * 4;
        float w1k[4], w2k[4], w3k[4];
#pragma unroll
        for (int kk = 0; kk < 4; ++kk) {
            w1k[kk] = sW1[(kb + kk) * HDIM + j];
            w2k[kk] = sW2[(kb + kk) * HDIM + j];
            w3k[kk] = sW3[(kb + kk) * HDIM + j];
        }
#pragma unroll
        for (int r = 0; r < 8; ++r) {
            float4 gv = sg4[(rg * 8 + r) * (HDIM / 4) + k4];
            float4 hv = sh4[(rg * 8 + r) * (HDIM / 4) + k4];
            t1[r] += gv.x * w1k[0] + gv.y * w1k[1] + gv.z * w1k[2] + gv.w * w1k[3];
            t2[r] += hv.x * w2k[0] + hv.y * w2k[1] + hv.z * w2k[2] + hv.w * w2k[3];
            t3[r] += hv.x * w3k[0] + hv.y * w3k[1] + hv.z * w3k[2] + hv.w * w3k[3];
        }
    }

    const float b1j = b1[j], b3j = b3[j];
#pragma unroll
    for (int r = 0; r < 8; ++r) {
        int row = row0 + rg * 8 + r;
        float deg = degw[row];
        float o = t1[r] + t3[r] - deg * t2[r] + deg * b1j + b3j;
        o = fmaxf(o, 0.f);
        size_t g = (size_t)row * HDIM + j;
        hout[g] = o;
        hbf[g]  = f32_to_bf16_rne(o);
    }
}

// ---------------------------------------------------------------------------
extern "C" void kernel_launch(void* const* d_in, const int* in_sizes, int n_in,
                              void* d_out, int out_size, void* d_ws, size_t ws_size,
                              hipStream_t stream)
{
    const float* x    = (const float*)d_in[0];
    const int*   eidx = (const int*)  d_in[1];   // (2, E) as int32
    const float* attr = (const float*)d_in[2];
    // d_in[3] = batch (unused)
    const float* Wemb = (const float*)d_in[4];
    const float* bemb = (const float*)d_in[5];
    const float* W1   = (const float*)d_in[6];
    const float* b1   = (const float*)d_in[7];
    const float* W2   = (const float*)d_in[8];
    const float* W3   = (const float*)d_in[9];
    const float* b3   = (const float*)d_in[10];

    float* h = (float*)d_out;                    // N x 64, in place

    // workspace: tmp ALIASES agg (disjoint lifetime: CSR build vs layers)
    float*    agg     = (float*)d_ws;                      // N*64 f32 (25.6 MB)
    int2*     tmp     = (int2*)d_ws;                       // E int2 (12.8 MB) — alias
    float*    degw    = agg + (size_t)NNODES * HDIM;       // N
    int*      rowptr  = (int*)(degw + NNODES);             // N+1
    int*      tileOff = rowptr + NNODES + 3;               // NTOT
    int2*     edgeS   = (int2*)(tileOff + NTOT + 2);       // E int2 (12.8 MB)
    ushort_t* hbf     = (ushort_t*)(edgeS + NEDGES);       // N*64 bf16 (12.8 MB)

    const int* srcI = eidx;
    const int* dstI = eidx + NEDGES;

    emb_kernel<<<NNODES / 32, 256, 0, stream>>>(x, Wemb, bemb, h, hbf);

    p1_hist<<<NT, 256, 0, stream>>>(dstI, tileOff);
    p2_scan<<<1, 1024, 0, stream>>>(tileOff);
    p3_bin <<<NT, 256, 0, stream>>>(srcI, dstI, attr, tileOff, tmp);
    p4_sort<<<NBUCK, 256, 0, stream>>>(tmp, tileOff, edgeS, rowptr);

    for (int l = 0; l < NLAYERS; ++l) {
        gather_kernel<<<NNODES * HDIM / 256, 256, 0, stream>>>(
            rowptr, edgeS, hbf, agg, degw);
        dense_kernel<<<NNODES / 32, 256, 0, stream>>>(
            h, agg, degw,
            W1 + (size_t)l * HDIM * HDIM, b1 + (size_t)l * HDIM,
            W2 + (size_t)l * HDIM * HDIM, W3 + (size_t)l * HDIM * HDIM,
            b3 + (size_t)l * HDIM, h, hbf);
    }
}

// Round 8
// 360.413 us; speedup vs baseline: 2.7977x; 1.1287x over previous
//
#include <hip/hip_runtime.h>

#define NNODES 100000
#define NEDGES 1600000
#define DINP   128
#define HDIM   64
#define NLAYERS 2

#define NBUCK 256
#define BDIV  391                              // nodes/bucket; 99999/391 = 255
#define TILE  8192
#define NT    ((NEDGES + TILE - 1) / TILE)     // 196 tiles
#define NTOT  (NBUCK * NT)                     // 50176
#define SEG   (NTOT / 1024)                    // 49 per scan thread (exact)

typedef unsigned short ushort_t;
typedef unsigned int   uint_t;

__device__ __forceinline__ ushort_t f32_to_bf16_rne(float x) {
    uint_t u = __float_as_uint(x);
    u = (u + 0x7FFFu + ((u >> 16) & 1u)) >> 16;
    return (ushort_t)u;
}
__device__ __forceinline__ float bf16_to_f32(ushort_t v) {
    return __uint_as_float(((uint_t)v) << 16);
}

// ---------------------------------------------------------------------------
// h0 = x @ W_emb + b_emb   — float4 LDS broadcasts, k unrolled by 4
// writes fp32 h and bf16 shadow hbf
// ---------------------------------------------------------------------------
__global__ __launch_bounds__(256) void emb_kernel(
    const float* __restrict__ x, const float* __restrict__ Wemb,
    const float* __restrict__ bemb, float* __restrict__ h,
    ushort_t* __restrict__ hbf)
{
    __shared__ float sW[DINP * HDIM];   // [k][j], 32 KB
    __shared__ float sx[32][DINP];      // 16 KB
    const int tid = threadIdx.x;
    const int row0 = blockIdx.x * 32;   // 100000 / 32 = 3125

    for (int i = tid; i < DINP * HDIM / 4; i += 256)
        ((float4*)sW)[i] = ((const float4*)Wemb)[i];
    for (int i = tid; i < 32 * DINP / 4; i += 256)
        ((float4*)sx)[i] = ((const float4*)(x + (size_t)row0 * DINP))[i];
    __syncthreads();

    const int j  = tid & 63;
    const int rg = tid >> 6;
    float acc[8];
    const float bj = bemb[j];
#pragma unroll
    for (int r = 0; r < 8; ++r) acc[r] = bj;

    const float4* sx4 = (const float4*)sx;      // row stride DINP/4 float4s
    for (int k4 = 0; k4 < DINP / 4; ++k4) {
        const int kb = k4 * 4;
        float w0 = sW[(kb + 0) * HDIM + j];
        float w1 = sW[(kb + 1) * HDIM + j];
        float w2 = sW[(kb + 2) * HDIM + j];
        float w3 = sW[(kb + 3) * HDIM + j];
#pragma unroll
        for (int r = 0; r < 8; ++r) {
            float4 xv = sx4[(rg * 8 + r) * (DINP / 4) + k4];
            acc[r] += xv.x * w0 + xv.y * w1 + xv.z * w2 + xv.w * w3;
        }
    }
#pragma unroll
    for (int r = 0; r < 8; ++r) {
        size_t g = (size_t)(row0 + rg * 8 + r) * HDIM + j;
        h[g]   = acc[r];
        hbf[g] = f32_to_bf16_rne(acc[r]);
    }
}

// ---------------------------------------------------------------------------
// CSR build, bucketed:
//  p1: per-(tile,bucket) histogram      p2: scan (bucket-major) -> offsets
//  p3: bin edges into tmp (packed key)  p4: per-bucket sort -> edgeS + rowptr
// ---------------------------------------------------------------------------
__global__ __launch_bounds__(256) void p1_hist(
    const int* __restrict__ dst, int* __restrict__ tileOff)
{
    __shared__ int hist[NBUCK];
    const int tl = blockIdx.x, t = threadIdx.x;
    hist[t] = 0;
    __syncthreads();
    const int base = tl * TILE;
#pragma unroll
    for (int i = 0; i < TILE / 256; ++i) {
        int e = base + i * 256 + t;
        if (e < NEDGES) atomicAdd(&hist[dst[e] / BDIV], 1);
    }
    __syncthreads();
    tileOff[t * NT + tl] = hist[t];     // bucket-major
}

// single-block exclusive scan over NTOT ints, in place
__global__ __launch_bounds__(1024) void p2_scan(int* __restrict__ tileOff)
{
    __shared__ int sd[1024];
    const int t = threadIdx.x;
    const int lo = t * SEG;
    int s = 0;
    for (int i = 0; i < SEG; ++i) s += tileOff[lo + i];
    sd[t] = s;
    __syncthreads();
    for (int off = 1; off < 1024; off <<= 1) {
        int v = (t >= off) ? sd[t - off] : 0;
        __syncthreads();
        sd[t] += v;
        __syncthreads();
    }
    int run = sd[t] - s;                // exclusive block prefix
    for (int i = 0; i < SEG; ++i) {
        int c = tileOff[lo + i];
        tileOff[lo + i] = run;
        run += c;
    }
}

// bin edges into tmp: key = (localdst << 17) | src, payload attr
__global__ __launch_bounds__(256) void p3_bin(
    const int* __restrict__ src, const int* __restrict__ dst,
    const float* __restrict__ attr, const int* __restrict__ tileOff,
    int2* __restrict__ tmp)
{
    __shared__ int cur[NBUCK];
    const int tl = blockIdx.x, t = threadIdx.x;
    cur[t] = tileOff[t * NT + tl];
    __syncthreads();
#pragma unroll
    for (int i = 0; i < TILE / 256; ++i) {
        int e = tl * TILE + i * 256 + t;
        if (e < NEDGES) {
            int d  = dst[e];
            int bk = d / BDIV;
            int ld = d - bk * BDIV;
            int pos = atomicAdd(&cur[bk], 1);
            int2 p;
            p.x = (ld << 17) | src[e];
            p.y = __float_as_int(attr[e]);
            tmp[pos] = p;
        }
    }
}

// per-bucket: local node hist + scan -> rowptr; scatter tmp -> edgeS
__global__ __launch_bounds__(256) void p4_sort(
    const int2* __restrict__ tmp, const int* __restrict__ tileOff,
    int2* __restrict__ edgeS, int* __restrict__ rowptr)
{
    __shared__ int sdh[512];            // padded hist/scan
    __shared__ int cur[BDIV + 1];
    const int b = blockIdx.x, t = threadIdx.x;
    const int n0 = b * BDIV;
    const int nn = (NNODES - n0 < BDIV) ? (NNODES - n0) : BDIV;
    const int ebeg = tileOff[b * NT];
    const int eend = (b + 1 < NBUCK) ? tileOff[(b + 1) * NT] : NEDGES;

    sdh[t] = 0; sdh[t + 256] = 0;
    __syncthreads();
    for (int e = ebeg + t; e < eend; e += 256)
        atomicAdd(&sdh[tmp[e].x >> 17], 1);
    __syncthreads();
    for (int off = 1; off < 512; off <<= 1) {
        int i0 = t, i1 = t + 256;
        int v0 = (i0 >= off) ? sdh[i0 - off] : 0;
        int v1 = (i1 >= off) ? sdh[i1 - off] : 0;
        __syncthreads();
        sdh[i0] += v0; sdh[i1] += v1;
        __syncthreads();
    }
    for (int i = t; i < nn; i += 256) {
        int c = ebeg + (i ? sdh[i - 1] : 0);
        cur[i] = c;
        rowptr[n0 + i] = c;
    }
    if (b == NBUCK - 1 && t == 0) rowptr[NNODES] = NEDGES;
    __syncthreads();
    for (int e = ebeg + t; e < eend; e += 256) {
        int2 w = tmp[e];
        int ld = w.x >> 17;
        int pos = atomicAdd(&cur[ld], 1);
        int2 p;
        p.x = w.x & 0x1FFFF;
        p.y = w.y;
        edgeS[pos] = p;
    }
}

// ---------------------------------------------------------------------------
// agg[v] = sum_{e: dst=v} w_e * hbf[src_e]; degw[v] = sum w_e
// VMEM-instruction-minimized: per 8 edges, 1 vector edge load (lane k holds
// edge i+k; readlane broadcasts) + 4 paired row loads (lane = uint = 2 bf16
// cols; lower half-wave reads even edge's row, upper half odd edge's row).
// Cross-half combine with shfl_xor(32).
// ---------------------------------------------------------------------------
#define GU 8
__global__ __launch_bounds__(256) void gather_kernel(
    const int* __restrict__ rowptr, const int2* __restrict__ edgeS,
    const ushort_t* __restrict__ hbf, float* __restrict__ agg,
    float* __restrict__ degw)
{
    const int gid  = blockIdx.x * 256 + threadIdx.x;
    const int v    = gid >> 6;
    const int lane = threadIdx.x & 63;
    const int half = lane >> 5;          // 0: even edge of pair, 1: odd
    const int sl   = lane & 31;          // column pair: cols 2sl, 2sl+1
    const int beg = rowptr[v], end = rowptr[v + 1];

    float accx = 0.f, accy = 0.f, wsum = 0.f;

    for (int i = beg; i < end; i += GU) {
        int idx = i + (lane & 7);
        int2 ev = edgeS[idx < end ? idx : beg];        // lane k: edge i+k
        float wl = (idx < end) ? __int_as_float(ev.y) : 0.f;
        int   sv = ev.x;
        int   wi = __float_as_int(wl);
#pragma unroll
        for (int j = 0; j < GU / 2; ++j) {
            int   s0 = __builtin_amdgcn_readlane(sv, 2 * j);
            int   s1 = __builtin_amdgcn_readlane(sv, 2 * j + 1);
            float w0 = __int_as_float(__builtin_amdgcn_readlane(wi, 2 * j));
            float w1 = __int_as_float(__builtin_amdgcn_readlane(wi, 2 * j + 1));
            int   row = half ? s1 : s0;
            float wv  = half ? w1 : w0;
            uint_t u = *(const uint_t*)(hbf + ((size_t)row << 6) + (sl << 1));
            float lo = __uint_as_float(u << 16);           // col 2*sl
            float hi = __uint_as_float(u & 0xFFFF0000u);   // col 2*sl+1
            accx += wv * lo;
            accy += wv * hi;
            wsum += wv;
        }
    }

    accx += __shfl_xor(accx, 32);
    accy += __shfl_xor(accy, 32);
    wsum += __shfl_xor(wsum, 32);

    if (half == 0) {
        float2 o; o.x = accx; o.y = accy;
        *(float2*)(agg + ((size_t)v << 6) + (sl << 1)) = o;
        if (sl == 0) degw[v] = wsum;
    }
}

// ---------------------------------------------------------------------------
// h = relu(agg @ W1 + h @ W3 - deg ⊙ (h @ W2) + deg·b1 + b3)   (in place)
// writes fp32 h and bf16 shadow hbf
// ---------------------------------------------------------------------------
__global__ __launch_bounds__(256) void dense_kernel(
    const float* __restrict__ hin, const float* __restrict__ agg,
    const float* __restrict__ degw,
    const float* __restrict__ W1, const float* __restrict__ b1,
    const float* __restrict__ W2, const float* __restrict__ W3,
    const float* __restrict__ b3, float* __restrict__ hout,
    ushort_t* __restrict__ hbf)
{
    __shared__ float sW1[HDIM * HDIM], sW2[HDIM * HDIM], sW3[HDIM * HDIM];
    __shared__ float sh[32][HDIM], sg[32][HDIM];
    const int tid = threadIdx.x;
    const int row0 = blockIdx.x * 32;

    for (int i = tid; i < HDIM * HDIM / 4; i += 256) {
        ((float4*)sW1)[i] = ((const float4*)W1)[i];
        ((float4*)sW2)[i] = ((const float4*)W2)[i];
        ((float4*)sW3)[i] = ((const float4*)W3)[i];
    }
    for (int i = tid; i < 32 * HDIM / 4; i += 256) {
        ((float4*)sh)[i] = ((const float4*)(hin + (size_t)row0 * HDIM))[i];
        ((float4*)sg)[i] = ((const float4*)(agg + (size_t)row0 * HDIM))[i];
    }
    __syncthreads();

    const int j  = tid & 63;
    const int rg = tid >> 6;
    float t1[8], t2[8], t3[8];
#pragma unroll
    for (int r = 0; r < 8; ++r) { t1[r] = 0.f; t2[r] = 0.f; t3[r] = 0.f; }

    const float4* sh4 = (const float4*)sh;   // row stride HDIM/4 float4s
    const float4* sg4 = (const float4*)sg;
    for (int k4 = 0; k4 < HDIM / 4; ++k4) {
        const int kb = k4 * 4;
        float w1k[4], w2k[4], w3k[4];
#pragma unroll
        for (int kk = 0; kk < 4; ++kk) {
            w1k[kk] = sW1[(kb + kk) * HDIM + j];
            w2k[kk] = sW2[(kb + kk) * HDIM + j];
            w3k[kk] = sW3[(kb + kk) * HDIM + j];
        }
#pragma unroll
        for (int r = 0; r < 8; ++r) {
            float4 gv = sg4[(rg * 8 + r) * (HDIM / 4) + k4];
            float4 hv = sh4[(rg * 8 + r) * (HDIM / 4) + k4];
            t1[r] += gv.x * w1k[0] + gv.y * w1k[1] + gv.z * w1k[2] + gv.w * w1k[3];
            t2[r] += hv.x * w2k[0] + hv.y * w2k[1] + hv.z * w2k[2] + hv.w * w2k[3];
            t3[r] += hv.x * w3k[0] + hv.y * w3k[1] + hv.z * w3k[2] + hv.w * w3k[3];
        }
    }

    const float b1j = b1[j], b3j = b3[j];
#pragma unroll
    for (int r = 0; r < 8; ++r) {
        int row = row0 + rg * 8 + r;
        float deg = degw[row];
        float o = t1[r] + t3[r] - deg * t2[r] + deg * b1j + b3j;
        o = fmaxf(o, 0.f);
        size_t g = (size_t)row * HDIM + j;
        hout[g] = o;
        hbf[g]  = f32_to_bf16_rne(o);
    }
}

// ---------------------------------------------------------------------------
extern "C" void kernel_launch(void* const* d_in, const int* in_sizes, int n_in,
                              void* d_out, int out_size, void* d_ws, size_t ws_size,
                              hipStream_t stream)
{
    const float* x    = (const float*)d_in[0];
    const int*   eidx = (const int*)  d_in[1];   // (2, E) as int32
    const float* attr = (const float*)d_in[2];
    // d_in[3] = batch (unused)
    const float* Wemb = (const float*)d_in[4];
    const float* bemb = (const float*)d_in[5];
    const float* W1   = (const float*)d_in[6];
    const float* b1   = (const float*)d_in[7];
    const float* W2   = (const float*)d_in[8];
    const float* W3   = (const float*)d_in[9];
    const float* b3   = (const float*)d_in[10];

    float* h = (float*)d_out;                    // N x 64, in place

    // workspace: tmp ALIASES agg (disjoint lifetime: CSR build vs layers)
    float*    agg     = (float*)d_ws;                      // N*64 f32 (25.6 MB)
    int2*     tmp     = (int2*)d_ws;                       // E int2 (12.8 MB) — alias
    float*    degw    = agg + (size_t)NNODES * HDIM;       // N
    int*      rowptr  = (int*)(degw + NNODES);             // N+1
    int*      tileOff = rowptr + NNODES + 4;               // NTOT (8B-aligned)
    int2*     edgeS   = (int2*)(tileOff + NTOT + 2);       // E int2 (8B-aligned)
    ushort_t* hbf     = (ushort_t*)(edgeS + NEDGES);       // N*64 bf16 (12.8 MB)

    const int* srcI = eidx;
    const int* dstI = eidx + NEDGES;

    emb_kernel<<<NNODES / 32, 256, 0, stream>>>(x, Wemb, bemb, h, hbf);

    p1_hist<<<NT, 256, 0, stream>>>(dstI, tileOff);
    p2_scan<<<1, 1024, 0, stream>>>(tileOff);
    p3_bin <<<NT, 256, 0, stream>>>(srcI, dstI, attr, tileOff, tmp);
    p4_sort<<<NBUCK, 256, 0, stream>>>(tmp, tileOff, edgeS, rowptr);

    for (int l = 0; l < NLAYERS; ++l) {
        gather_kernel<<<NNODES * HDIM / 256, 256, 0, stream>>>(
            rowptr, edgeS, hbf, agg, degw);
        dense_kernel<<<NNODES / 32, 256, 0, stream>>>(
            h, agg, degw,
            W1 + (size_t)l * HDIM * HDIM, b1 + (size_t)l * HDIM,
            W2 + (size_t)l * HDIM * HDIM, W3 + (size_t)l * HDIM * HDIM,
            b3 + (size_t)l * HDIM, h, hbf);
    }
}

// Round 9
// 263.835 us; speedup vs baseline: 3.8218x; 1.3661x over previous
//
#include <hip/hip_runtime.h>

#define NNODES 100000
#define NEDGES 1600000
#define DINP   128
#define HDIM   64
#define NLAYERS 2

#define NBUCK 256
#define BDIV  391
#define TILE  8192
#define NT    ((NEDGES + TILE - 1) / TILE)     // 196
#define NTOT  (NBUCK * NT)                     // 50176
#define SEG   (NTOT / 1024)                    // 49

typedef unsigned short ushort_t;
typedef unsigned int   uint_t;
typedef __attribute__((ext_vector_type(8))) short bf16x8;
typedef __attribute__((ext_vector_type(4))) float f32x4;

__device__ __forceinline__ ushort_t f32_to_bf16_rne(float x) {
    uint_t u = __float_as_uint(x);
    u = (u + 0x7FFFu + ((u >> 16) & 1u)) >> 16;
    return (ushort_t)u;
}
__device__ __forceinline__ float bf16_to_f32(ushort_t v) {
    return __uint_as_float(((uint_t)v) << 16);
}

// ---------------------------------------------------------------------------
// h0 = x @ W_emb + b_emb  -> bf16 hbf only (fp32 h is dead downstream)
// ---------------------------------------------------------------------------
__global__ __launch_bounds__(256) void emb_kernel(
    const float* __restrict__ x, const float* __restrict__ Wemb,
    const float* __restrict__ bemb, ushort_t* __restrict__ hbf)
{
    __shared__ float sW[DINP * HDIM];
    __shared__ float sx[32][DINP];
    const int tid = threadIdx.x;
    const int row0 = blockIdx.x * 32;

    for (int i = tid; i < DINP * HDIM / 4; i += 256)
        ((float4*)sW)[i] = ((const float4*)Wemb)[i];
    for (int i = tid; i < 32 * DINP / 4; i += 256)
        ((float4*)sx)[i] = ((const float4*)(x + (size_t)row0 * DINP))[i];
    __syncthreads();

    const int j  = tid & 63;
    const int rg = tid >> 6;
    float acc[8];
    const float bj = bemb[j];
#pragma unroll
    for (int r = 0; r < 8; ++r) acc[r] = bj;

    const float4* sx4 = (const float4*)sx;
    for (int k4 = 0; k4 < DINP / 4; ++k4) {
        const int kb = k4 * 4;
        float w0 = sW[(kb + 0) * HDIM + j];
        float w1 = sW[(kb + 1) * HDIM + j];
        float w2 = sW[(kb + 2) * HDIM + j];
        float w3 = sW[(kb + 3) * HDIM + j];
#pragma unroll
        for (int r = 0; r < 8; ++r) {
            float4 xv = sx4[(rg * 8 + r) * (DINP / 4) + k4];
            acc[r] += xv.x * w0 + xv.y * w1 + xv.z * w2 + xv.w * w3;
        }
    }
#pragma unroll
    for (int r = 0; r < 8; ++r)
        hbf[(size_t)(row0 + rg * 8 + r) * HDIM + j] = f32_to_bf16_rne(acc[r]);
}

// ---------------------------------------------------------------------------
// wprep: build B-fragments (bf16 hi/lo split) for all layers/mats in MFMA
// frag layout: [layer][mv=mat*2+(0hi|1lo)][kb][nt][lane][j]  (ushort)
// B mapping for mfma_f32_16x16x32_bf16: col = lane&15, k = 8*(lane>>4)+j
// ---------------------------------------------------------------------------
__global__ __launch_bounds__(256) void wprep_kernel(
    const float* __restrict__ W1, const float* __restrict__ W2,
    const float* __restrict__ W3, ushort_t* __restrict__ wfrag)
{
    int t = blockIdx.x * 256 + threadIdx.x;       // 48 blocks: 2*3*2*4*64*8/2... t < 24576
    if (t >= 2 * 3 * 2 * 4 * 64 * 8) return;
    int j    = t & 7;
    int l    = (t >> 3) & 63;
    int nt   = (t >> 9) & 3;
    int kb   = (t >> 11) & 1;
    int mat  = (t >> 12) % 3;
    int layer = t / 12288;

    int k = kb * 32 + 8 * (l >> 4) + j;
    int n = nt * 16 + (l & 15);
    const float* Wm = (mat == 0) ? W1 : (mat == 1) ? W2 : W3;
    float w = Wm[(size_t)layer * HDIM * HDIM + k * HDIM + n];
    ushort_t hi = f32_to_bf16_rne(w);
    ushort_t lo = f32_to_bf16_rne(w - bf16_to_f32(hi));

    size_t base = (size_t)layer * 24576;
    size_t idxh = base + ((((size_t)(mat * 2 + 0) * 2 + kb) * 4 + nt) * 64 + l) * 8 + j;
    size_t idxl = base + ((((size_t)(mat * 2 + 1) * 2 + kb) * 4 + nt) * 64 + l) * 8 + j;
    wfrag[idxh] = hi;
    wfrag[idxl] = lo;
}

// ---------------------------------------------------------------------------
// CSR build (unchanged): p1 hist -> p2 scan -> p3 bin -> p4 sort
// ---------------------------------------------------------------------------
__global__ __launch_bounds__(256) void p1_hist(
    const int* __restrict__ dst, int* __restrict__ tileOff)
{
    __shared__ int hist[NBUCK];
    const int tl = blockIdx.x, t = threadIdx.x;
    hist[t] = 0;
    __syncthreads();
    const int base = tl * TILE;
#pragma unroll
    for (int i = 0; i < TILE / 256; ++i) {
        int e = base + i * 256 + t;
        if (e < NEDGES) atomicAdd(&hist[dst[e] / BDIV], 1);
    }
    __syncthreads();
    tileOff[t * NT + tl] = hist[t];
}

__global__ __launch_bounds__(1024) void p2_scan(int* __restrict__ tileOff)
{
    __shared__ int sd[1024];
    const int t = threadIdx.x;
    const int lo = t * SEG;
    int s = 0;
    for (int i = 0; i < SEG; ++i) s += tileOff[lo + i];
    sd[t] = s;
    __syncthreads();
    for (int off = 1; off < 1024; off <<= 1) {
        int v = (t >= off) ? sd[t - off] : 0;
        __syncthreads();
        sd[t] += v;
        __syncthreads();
    }
    int run = sd[t] - s;
    for (int i = 0; i < SEG; ++i) {
        int c = tileOff[lo + i];
        tileOff[lo + i] = run;
        run += c;
    }
}

__global__ __launch_bounds__(256) void p3_bin(
    const int* __restrict__ src, const int* __restrict__ dst,
    const float* __restrict__ attr, const int* __restrict__ tileOff,
    int2* __restrict__ tmp)
{
    __shared__ int cur[NBUCK];
    const int tl = blockIdx.x, t = threadIdx.x;
    cur[t] = tileOff[t * NT + tl];
    __syncthreads();
#pragma unroll
    for (int i = 0; i < TILE / 256; ++i) {
        int e = tl * TILE + i * 256 + t;
        if (e < NEDGES) {
            int d  = dst[e];
            int bk = d / BDIV;
            int ld = d - bk * BDIV;
            int pos = atomicAdd(&cur[bk], 1);
            int2 p;
            p.x = (ld << 17) | src[e];
            p.y = __float_as_int(attr[e]);
            tmp[pos] = p;
        }
    }
}

__global__ __launch_bounds__(256) void p4_sort(
    const int2* __restrict__ tmp, const int* __restrict__ tileOff,
    int2* __restrict__ edgeS, int* __restrict__ rowptr)
{
    __shared__ int sdh[512];
    __shared__ int cur[BDIV + 1];
    const int b = blockIdx.x, t = threadIdx.x;
    const int n0 = b * BDIV;
    const int nn = (NNODES - n0 < BDIV) ? (NNODES - n0) : BDIV;
    const int ebeg = tileOff[b * NT];
    const int eend = (b + 1 < NBUCK) ? tileOff[(b + 1) * NT] : NEDGES;

    sdh[t] = 0; sdh[t + 256] = 0;
    __syncthreads();
    for (int e = ebeg + t; e < eend; e += 256)
        atomicAdd(&sdh[tmp[e].x >> 17], 1);
    __syncthreads();
    for (int off = 1; off < 512; off <<= 1) {
        int i0 = t, i1 = t + 256;
        int v0 = (i0 >= off) ? sdh[i0 - off] : 0;
        int v1 = (i1 >= off) ? sdh[i1 - off] : 0;
        __syncthreads();
        sdh[i0] += v0; sdh[i1] += v1;
        __syncthreads();
    }
    for (int i = t; i < nn; i += 256) {
        int c = ebeg + (i ? sdh[i - 1] : 0);
        cur[i] = c;
        rowptr[n0 + i] = c;
    }
    if (b == NBUCK - 1 && t == 0) rowptr[NNODES] = NEDGES;
    __syncthreads();
    for (int e = ebeg + t; e < eend; e += 256) {
        int2 w = tmp[e];
        int ld = w.x >> 17;
        int pos = atomicAdd(&cur[ld], 1);
        int2 p;
        p.x = w.x & 0x1FFFF;
        p.y = w.y;
        edgeS[pos] = p;
    }
}

// ---------------------------------------------------------------------------
// gather: aggbf[v] = bf16( sum w_e * hbf[src_e] ), degw[v] = sum w_e
// ---------------------------------------------------------------------------
#define GU 8
__global__ __launch_bounds__(256) void gather_kernel(
    const int* __restrict__ rowptr, const int2* __restrict__ edgeS,
    const ushort_t* __restrict__ hbf, ushort_t* __restrict__ aggbf,
    float* __restrict__ degw)
{
    const int gid  = blockIdx.x * 256 + threadIdx.x;
    const int v    = gid >> 6;
    const int lane = threadIdx.x & 63;
    const int half = lane >> 5;
    const int sl   = lane & 31;
    const int beg = rowptr[v], end = rowptr[v + 1];

    float accx = 0.f, accy = 0.f, wsum = 0.f;

    for (int i = beg; i < end; i += GU) {
        int idx = i + (lane & 7);
        int2 ev = edgeS[idx < end ? idx : beg];
        float wl = (idx < end) ? __int_as_float(ev.y) : 0.f;
        int   sv = ev.x;
        int   wi = __float_as_int(wl);
#pragma unroll
        for (int j = 0; j < GU / 2; ++j) {
            int   s0 = __builtin_amdgcn_readlane(sv, 2 * j);
            int   s1 = __builtin_amdgcn_readlane(sv, 2 * j + 1);
            float w0 = __int_as_float(__builtin_amdgcn_readlane(wi, 2 * j));
            float w1 = __int_as_float(__builtin_amdgcn_readlane(wi, 2 * j + 1));
            int   row = half ? s1 : s0;
            float wv  = half ? w1 : w0;
            uint_t u = *(const uint_t*)(hbf + ((size_t)row << 6) + (sl << 1));
            float lo = __uint_as_float(u << 16);
            float hi = __uint_as_float(u & 0xFFFF0000u);
            accx += wv * lo;
            accy += wv * hi;
            wsum += wv;
        }
    }

    accx += __shfl_xor(accx, 32);
    accy += __shfl_xor(accy, 32);
    wsum += __shfl_xor(wsum, 32);

    if (half == 0) {
        uint_t packed = (uint_t)f32_to_bf16_rne(accx)
                      | ((uint_t)f32_to_bf16_rne(accy) << 16);
        *(uint_t*)(aggbf + ((size_t)v << 6) + (sl << 1)) = packed;
        if (sl == 0) degw[v] = wsum;
    }
}

// ---------------------------------------------------------------------------
// dense via MFMA: out = relu(agg@W1 + h@W3 - deg*(h@W2) + deg*b1 + b3)
// wave = 16 rows x 64 cols; 48 mfma_f32_16x16x32_bf16 (3 mats x hi/lo x kb x nt)
// A: row = lane&15, k = 8*(lane>>4)+j (contiguous ushort8 in row-major bf16)
// no LDS, no barriers
// ---------------------------------------------------------------------------
template<int WRITE_BF>
__global__ __launch_bounds__(256) void dense_mfma(
    const ushort_t* __restrict__ hbf, const ushort_t* __restrict__ aggbf,
    const float* __restrict__ degw, const ushort_t* __restrict__ wfrag,
    const float* __restrict__ b1, const float* __restrict__ b3,
    float* __restrict__ hout, ushort_t* __restrict__ hbf_out)
{
    const int wid = blockIdx.x * 4 + (threadIdx.x >> 6);
    if (wid >= NNODES / 16) return;
    const int lane = threadIdx.x & 63;
    const int lrow = lane & 15;
    const int lgrp = lane >> 4;
    const int r0   = wid * 16;

    f32x4 acc[3][4];
#pragma unroll
    for (int m = 0; m < 3; ++m)
#pragma unroll
        for (int nt = 0; nt < 4; ++nt)
            acc[m][nt] = (f32x4){0.f, 0.f, 0.f, 0.f};

#pragma unroll
    for (int kb = 0; kb < 2; ++kb) {
        const size_t aoff = ((size_t)(r0 + lrow) << 6) + kb * 32 + lgrp * 8;
        bf16x8 a_agg = *(const bf16x8*)(aggbf + aoff);
        bf16x8 a_h   = *(const bf16x8*)(hbf + aoff);
#pragma unroll
        for (int mv = 0; mv < 6; ++mv) {
            const int mat = mv >> 1;
            bf16x8 a = (mat == 0) ? a_agg : a_h;
            const ushort_t* wb = wfrag + (((size_t)mv * 2 + kb) * 4) * 512 + lane * 8;
#pragma unroll
            for (int nt = 0; nt < 4; ++nt) {
                bf16x8 b = *(const bf16x8*)(wb + nt * 512);
                acc[mat][nt] = __builtin_amdgcn_mfma_f32_16x16x32_bf16(
                    a, b, acc[mat][nt], 0, 0, 0);
            }
        }
    }

    float dreg[4];
#pragma unroll
    for (int r = 0; r < 4; ++r) dreg[r] = degw[r0 + lgrp * 4 + r];

#pragma unroll
    for (int nt = 0; nt < 4; ++nt) {
        int col = nt * 16 + lrow;
        float b1c = b1[col], b3c = b3[col];
#pragma unroll
        for (int r = 0; r < 4; ++r) {
            int row = r0 + lgrp * 4 + r;
            float o = acc[0][nt][r] + acc[2][nt][r] - dreg[r] * acc[1][nt][r]
                    + dreg[r] * b1c + b3c;
            o = fmaxf(o, 0.f);
            if (WRITE_BF)
                hbf_out[((size_t)row << 6) + col] = f32_to_bf16_rne(o);
            else
                hout[((size_t)row << 6) + col] = o;
        }
    }
}

// ---------------------------------------------------------------------------
extern "C" void kernel_launch(void* const* d_in, const int* in_sizes, int n_in,
                              void* d_out, int out_size, void* d_ws, size_t ws_size,
                              hipStream_t stream)
{
    const float* x    = (const float*)d_in[0];
    const int*   eidx = (const int*)  d_in[1];
    const float* attr = (const float*)d_in[2];
    const float* Wemb = (const float*)d_in[4];
    const float* bemb = (const float*)d_in[5];
    const float* W1   = (const float*)d_in[6];
    const float* b1   = (const float*)d_in[7];
    const float* W2   = (const float*)d_in[8];
    const float* W3   = (const float*)d_in[9];
    const float* b3   = (const float*)d_in[10];

    float* hout = (float*)d_out;

    // workspace layout (units of 4B; all region starts 16B-aligned)
    float*    degw    = (float*)d_ws;                            // @0, N
    int*      rowptr  = (int*)d_ws + 100000;                     // N+1
    int*      tileOff = (int*)d_ws + 200016;                     // NTOT
    int2*     edgeS   = (int2*)((int*)d_ws + 250192);            // E int2
    ushort_t* hbf     = (ushort_t*)((int*)d_ws + 3450192);       // N*64 bf16
    ushort_t* aggbf   = (ushort_t*)((int*)d_ws + 6650192);       // N*64 bf16
    int2*     tmp     = (int2*)aggbf;                            // alias (CSR build only)
    ushort_t* wfrag   = (ushort_t*)((int*)d_ws + 9850192);       // 49152 ushorts

    const int* srcI = eidx;
    const int* dstI = eidx + NEDGES;

    emb_kernel  <<<NNODES / 32, 256, 0, stream>>>(x, Wemb, bemb, hbf);
    wprep_kernel<<<96, 256, 0, stream>>>(W1, W2, W3, wfrag);

    p1_hist<<<NT, 256, 0, stream>>>(dstI, tileOff);
    p2_scan<<<1, 1024, 0, stream>>>(tileOff);
    p3_bin <<<NT, 256, 0, stream>>>(srcI, dstI, attr, tileOff, tmp);
    p4_sort<<<NBUCK, 256, 0, stream>>>(tmp, tileOff, edgeS, rowptr);

    const int denseGrid = (NNODES / 16 + 3) / 4;   // 1563
    // layer 0: writes hbf (in place, wave-local rows only)
    gather_kernel<<<NNODES * HDIM / 256, 256, 0, stream>>>(
        rowptr, edgeS, hbf, aggbf, degw);
    dense_mfma<1><<<denseGrid, 256, 0, stream>>>(
        hbf, aggbf, degw, wfrag, b1, b3, hout, hbf);
    // layer 1: writes fp32 output
    gather_kernel<<<NNODES * HDIM / 256, 256, 0, stream>>>(
        rowptr, edgeS, hbf, aggbf, degw);
    dense_mfma<0><<<denseGrid, 256, 0, stream>>>(
        hbf, aggbf, degw, wfrag + 24576, b1 + HDIM, b3 + HDIM, hout, hbf);
}

// Round 10
// 243.044 us; speedup vs baseline: 4.1487x; 1.0855x over previous
//
#include <hip/hip_runtime.h>

#define NNODES 100000
#define NEDGES 1600000
#define DINP   128
#define HDIM   64
#define NLAYERS 2

#define NBUCK 256
#define BDIV  391
#define TILE  8192
#define NT    ((NEDGES + TILE - 1) / TILE)     // 196
#define NTOT  (NBUCK * NT)                     // 50176
#define SEG   (NTOT / 1024)                    // 49

typedef unsigned short ushort_t;
typedef unsigned int   uint_t;
typedef __attribute__((ext_vector_type(8))) short bf16x8;
typedef __attribute__((ext_vector_type(4))) float f32x4;

__device__ __forceinline__ ushort_t f32_to_bf16_rne(float x) {
    uint_t u = __float_as_uint(x);
    u = (u + 0x7FFFu + ((u >> 16) & 1u)) >> 16;
    return (ushort_t)u;
}
__device__ __forceinline__ float bf16_to_f32(ushort_t v) {
    return __uint_as_float(((uint_t)v) << 16);
}

// ---------------------------------------------------------------------------
// wprep_emb: B-fragments for W_emb (128x64), hi/lo split
// layout: [hl][kb(4)][nt(4)][lane(64)][j(8)]  -> 16384 ushorts
// ---------------------------------------------------------------------------
__global__ __launch_bounds__(256) void wprep_emb(
    const float* __restrict__ Wemb, ushort_t* __restrict__ wefrag)
{
    int t = blockIdx.x * 256 + threadIdx.x;
    if (t >= 4 * 4 * 64 * 8) return;           // 8192 (hi+lo written together)
    int j  = t & 7;
    int l  = (t >> 3) & 63;
    int nt = (t >> 9) & 3;
    int kb = (t >> 11) & 3;
    int k = kb * 32 + 8 * (l >> 4) + j;
    int n = nt * 16 + (l & 15);
    float w = Wemb[k * HDIM + n];
    ushort_t hi = f32_to_bf16_rne(w);
    ushort_t lo = f32_to_bf16_rne(w - bf16_to_f32(hi));
    wefrag[(((0 * 4 + kb) * 4 + nt) * 64 + l) * 8 + j] = hi;
    wefrag[(((1 * 4 + kb) * 4 + nt) * 64 + l) * 8 + j] = lo;
}

// ---------------------------------------------------------------------------
// emb via MFMA: hbf = bf16(x @ W_emb + b_emb)
// wave = 16 rows x 64 cols; x hi/lo built in-register; 48 MFMA/wave; no LDS
// ---------------------------------------------------------------------------
__global__ __launch_bounds__(256) void emb_mfma(
    const float* __restrict__ x, const ushort_t* __restrict__ wefrag,
    const float* __restrict__ bemb, ushort_t* __restrict__ hbf)
{
    const int wid = blockIdx.x * 4 + (threadIdx.x >> 6);
    if (wid >= NNODES / 16) return;             // 6250 waves
    const int lane = threadIdx.x & 63;
    const int lrow = lane & 15;
    const int lgrp = lane >> 4;
    const int r0 = wid * 16;

    f32x4 acc[4];
#pragma unroll
    for (int nt = 0; nt < 4; ++nt) acc[nt] = (f32x4){0.f, 0.f, 0.f, 0.f};

#pragma unroll
    for (int kb = 0; kb < 4; ++kb) {
        const float* xp = x + (size_t)(r0 + lrow) * DINP + kb * 32 + lgrp * 8;
        float4 xa = *(const float4*)xp;
        float4 xb = *(const float4*)(xp + 4);
        float xs[8] = {xa.x, xa.y, xa.z, xa.w, xb.x, xb.y, xb.z, xb.w};
        bf16x8 xhi, xlo;
#pragma unroll
        for (int q = 0; q < 8; ++q) {
            ushort_t hv = f32_to_bf16_rne(xs[q]);
            xhi[q] = (short)hv;
            xlo[q] = (short)f32_to_bf16_rne(xs[q] - bf16_to_f32(hv));
        }
#pragma unroll
        for (int nt = 0; nt < 4; ++nt) {
            bf16x8 bhi = *(const bf16x8*)(wefrag + (((0 * 4 + kb) * 4 + nt) * 64 + lane) * 8);
            bf16x8 blo = *(const bf16x8*)(wefrag + (((1 * 4 + kb) * 4 + nt) * 64 + lane) * 8);
            acc[nt] = __builtin_amdgcn_mfma_f32_16x16x32_bf16(xhi, bhi, acc[nt], 0, 0, 0);
            acc[nt] = __builtin_amdgcn_mfma_f32_16x16x32_bf16(xlo, bhi, acc[nt], 0, 0, 0);
            acc[nt] = __builtin_amdgcn_mfma_f32_16x16x32_bf16(xhi, blo, acc[nt], 0, 0, 0);
        }
    }

#pragma unroll
    for (int nt = 0; nt < 4; ++nt) {
        int col = nt * 16 + lrow;
        float bc = bemb[col];
#pragma unroll
        for (int r = 0; r < 4; ++r) {
            int row = r0 + lgrp * 4 + r;
            hbf[((size_t)row << 6) + col] = f32_to_bf16_rne(acc[nt][r] + bc);
        }
    }
}

// ---------------------------------------------------------------------------
// wprep: B-fragments (bf16 hi/lo) for W1/W2/W3, both layers
// ---------------------------------------------------------------------------
__global__ __launch_bounds__(256) void wprep_kernel(
    const float* __restrict__ W1, const float* __restrict__ W2,
    const float* __restrict__ W3, ushort_t* __restrict__ wfrag)
{
    int t = blockIdx.x * 256 + threadIdx.x;
    if (t >= 2 * 3 * 2 * 4 * 64 * 8) return;
    int j    = t & 7;
    int l    = (t >> 3) & 63;
    int nt   = (t >> 9) & 3;
    int kb   = (t >> 11) & 1;
    int mat  = (t >> 12) % 3;
    int layer = t / 12288;

    int k = kb * 32 + 8 * (l >> 4) + j;
    int n = nt * 16 + (l & 15);
    const float* Wm = (mat == 0) ? W1 : (mat == 1) ? W2 : W3;
    float w = Wm[(size_t)layer * HDIM * HDIM + k * HDIM + n];
    ushort_t hi = f32_to_bf16_rne(w);
    ushort_t lo = f32_to_bf16_rne(w - bf16_to_f32(hi));

    size_t base = (size_t)layer * 24576;
    size_t idxh = base + ((((size_t)(mat * 2 + 0) * 2 + kb) * 4 + nt) * 64 + l) * 8 + j;
    size_t idxl = base + ((((size_t)(mat * 2 + 1) * 2 + kb) * 4 + nt) * 64 + l) * 8 + j;
    wfrag[idxh] = hi;
    wfrag[idxl] = lo;
}

// ---------------------------------------------------------------------------
// CSR build: p1 hist -> p2 scan -> p3 bin -> p4 sort
// ---------------------------------------------------------------------------
__global__ __launch_bounds__(256) void p1_hist(
    const int* __restrict__ dst, int* __restrict__ tileOff)
{
    __shared__ int hist[NBUCK];
    const int tl = blockIdx.x, t = threadIdx.x;
    hist[t] = 0;
    __syncthreads();
    const int base = tl * TILE;
#pragma unroll
    for (int i = 0; i < TILE / 256; ++i) {
        int e = base + i * 256 + t;
        if (e < NEDGES) atomicAdd(&hist[dst[e] / BDIV], 1);
    }
    __syncthreads();
    tileOff[t * NT + tl] = hist[t];
}

__global__ __launch_bounds__(1024) void p2_scan(int* __restrict__ tileOff)
{
    __shared__ int sd[1024];
    const int t = threadIdx.x;
    const int lo = t * SEG;
    int s = 0;
    for (int i = 0; i < SEG; ++i) s += tileOff[lo + i];
    sd[t] = s;
    __syncthreads();
    for (int off = 1; off < 1024; off <<= 1) {
        int v = (t >= off) ? sd[t - off] : 0;
        __syncthreads();
        sd[t] += v;
        __syncthreads();
    }
    int run = sd[t] - s;
    for (int i = 0; i < SEG; ++i) {
        int c = tileOff[lo + i];
        tileOff[lo + i] = run;
        run += c;
    }
}

__global__ __launch_bounds__(256) void p3_bin(
    const int* __restrict__ src, const int* __restrict__ dst,
    const float* __restrict__ attr, const int* __restrict__ tileOff,
    int2* __restrict__ tmp)
{
    __shared__ int cur[NBUCK];
    const int tl = blockIdx.x, t = threadIdx.x;
    cur[t] = tileOff[t * NT + tl];
    __syncthreads();
#pragma unroll
    for (int i = 0; i < TILE / 256; ++i) {
        int e = tl * TILE + i * 256 + t;
        if (e < NEDGES) {
            int d  = dst[e];
            int bk = d / BDIV;
            int ld = d - bk * BDIV;
            int pos = atomicAdd(&cur[bk], 1);
            int2 p;
            p.x = (ld << 17) | src[e];
            p.y = __float_as_int(attr[e]);
            tmp[pos] = p;
        }
    }
}

__global__ __launch_bounds__(256) void p4_sort(
    const int2* __restrict__ tmp, const int* __restrict__ tileOff,
    int2* __restrict__ edgeS, int* __restrict__ rowptr)
{
    __shared__ int sdh[512];
    __shared__ int cur[BDIV + 1];
    const int b = blockIdx.x, t = threadIdx.x;
    const int n0 = b * BDIV;
    const int nn = (NNODES - n0 < BDIV) ? (NNODES - n0) : BDIV;
    const int ebeg = tileOff[b * NT];
    const int eend = (b + 1 < NBUCK) ? tileOff[(b + 1) * NT] : NEDGES;

    sdh[t] = 0; sdh[t + 256] = 0;
    __syncthreads();
    for (int e = ebeg + t; e < eend; e += 256)
        atomicAdd(&sdh[tmp[e].x >> 17], 1);
    __syncthreads();
    for (int off = 1; off < 512; off <<= 1) {
        int i0 = t, i1 = t + 256;
        int v0 = (i0 >= off) ? sdh[i0 - off] : 0;
        int v1 = (i1 >= off) ? sdh[i1 - off] : 0;
        __syncthreads();
        sdh[i0] += v0; sdh[i1] += v1;
        __syncthreads();
    }
    for (int i = t; i < nn; i += 256) {
        int c = ebeg + (i ? sdh[i - 1] : 0);
        cur[i] = c;
        rowptr[n0 + i] = c;
    }
    if (b == NBUCK - 1 && t == 0) rowptr[NNODES] = NEDGES;
    __syncthreads();
    for (int e = ebeg + t; e < eend; e += 256) {
        int2 w = tmp[e];
        int ld = w.x >> 17;
        int pos = atomicAdd(&cur[ld], 1);
        int2 p;
        p.x = w.x & 0x1FFFF;
        p.y = w.y;
        edgeS[pos] = p;
    }
}

// ---------------------------------------------------------------------------
// gather: aggbf[v] = bf16( sum w_e * hbf[src_e] ), degw[v] = sum w_e
// quad-row loads: one uint2/lane instruction reads 4 rows (16 lanes/row);
// edge-of-quarter selected via readlane broadcasts + cndmask chain.
// ---------------------------------------------------------------------------
__global__ __launch_bounds__(256) void gather_kernel(
    const int* __restrict__ rowptr, const int2* __restrict__ edgeS,
    const ushort_t* __restrict__ hbf, ushort_t* __restrict__ aggbf,
    float* __restrict__ degw)
{
    const int gid  = blockIdx.x * 256 + threadIdx.x;
    const int v    = gid >> 6;
    const int lane = threadIdx.x & 63;
    const int qtr  = lane >> 4;          // which edge of the 4-group
    const int ql   = lane & 15;          // cols 4*ql .. 4*ql+3
    const int beg = rowptr[v], end = rowptr[v + 1];

    float a0 = 0.f, a1 = 0.f, a2 = 0.f, a3 = 0.f, wsum = 0.f;

    for (int i = beg; i < end; i += 8) {
        int idx = i + (lane & 7);
        int2 ev = edgeS[idx < end ? idx : beg];
        float wl = (idx < end) ? __int_as_float(ev.y) : 0.f;
        int sv = ev.x;
        int wi = __float_as_int(wl);
#pragma unroll
        for (int j = 0; j < 2; ++j) {
            int s0 = __builtin_amdgcn_readlane(sv, 4 * j + 0);
            int s1 = __builtin_amdgcn_readlane(sv, 4 * j + 1);
            int s2 = __builtin_amdgcn_readlane(sv, 4 * j + 2);
            int s3 = __builtin_amdgcn_readlane(sv, 4 * j + 3);
            int w0 = __builtin_amdgcn_readlane(wi, 4 * j + 0);
            int w1 = __builtin_amdgcn_readlane(wi, 4 * j + 1);
            int w2 = __builtin_amdgcn_readlane(wi, 4 * j + 2);
            int w3 = __builtin_amdgcn_readlane(wi, 4 * j + 3);
            int row = (qtr == 0) ? s0 : (qtr == 1) ? s1 : (qtr == 2) ? s2 : s3;
            int wvi = (qtr == 0) ? w0 : (qtr == 1) ? w1 : (qtr == 2) ? w2 : w3;
            float wv = __int_as_float(wvi);
            uint2 u = *(const uint2*)(hbf + ((size_t)row << 6) + (ql << 2));
            a0 += wv * __uint_as_float(u.x << 16);
            a1 += wv * __uint_as_float(u.x & 0xFFFF0000u);
            a2 += wv * __uint_as_float(u.y << 16);
            a3 += wv * __uint_as_float(u.y & 0xFFFF0000u);
            wsum += wv;
        }
    }

    // reduce across the 4 quarters (lane bits 4 and 5)
    a0 += __shfl_xor(a0, 16);  a0 += __shfl_xor(a0, 32);
    a1 += __shfl_xor(a1, 16);  a1 += __shfl_xor(a1, 32);
    a2 += __shfl_xor(a2, 16);  a2 += __shfl_xor(a2, 32);
    a3 += __shfl_xor(a3, 16);  a3 += __shfl_xor(a3, 32);
    wsum += __shfl_xor(wsum, 16);  wsum += __shfl_xor(wsum, 32);

    if (qtr == 0) {
        uint2 o;
        o.x = (uint_t)f32_to_bf16_rne(a0) | ((uint_t)f32_to_bf16_rne(a1) << 16);
        o.y = (uint_t)f32_to_bf16_rne(a2) | ((uint_t)f32_to_bf16_rne(a3) << 16);
        *(uint2*)(aggbf + ((size_t)v << 6) + (ql << 2)) = o;
        if (ql == 0) degw[v] = wsum;
    }
}

// ---------------------------------------------------------------------------
// dense via MFMA: out = relu(agg@W1 + h@W3 - deg*(h@W2) + deg*b1 + b3)
// ---------------------------------------------------------------------------
template<int WRITE_BF>
__global__ __launch_bounds__(256) void dense_mfma(
    const ushort_t* __restrict__ hbf, const ushort_t* __restrict__ aggbf,
    const float* __restrict__ degw, const ushort_t* __restrict__ wfrag,
    const float* __restrict__ b1, const float* __restrict__ b3,
    float* __restrict__ hout, ushort_t* __restrict__ hbf_out)
{
    const int wid = blockIdx.x * 4 + (threadIdx.x >> 6);
    if (wid >= NNODES / 16) return;
    const int lane = threadIdx.x & 63;
    const int lrow = lane & 15;
    const int lgrp = lane >> 4;
    const int r0   = wid * 16;

    f32x4 acc[3][4];
#pragma unroll
    for (int m = 0; m < 3; ++m)
#pragma unroll
        for (int nt = 0; nt < 4; ++nt)
            acc[m][nt] = (f32x4){0.f, 0.f, 0.f, 0.f};

#pragma unroll
    for (int kb = 0; kb < 2; ++kb) {
        const size_t aoff = ((size_t)(r0 + lrow) << 6) + kb * 32 + lgrp * 8;
        bf16x8 a_agg = *(const bf16x8*)(aggbf + aoff);
        bf16x8 a_h   = *(const bf16x8*)(hbf + aoff);
#pragma unroll
        for (int mv = 0; mv < 6; ++mv) {
            const int mat = mv >> 1;
            bf16x8 a = (mat == 0) ? a_agg : a_h;
            const ushort_t* wb = wfrag + (((size_t)mv * 2 + kb) * 4) * 512 + lane * 8;
#pragma unroll
            for (int nt = 0; nt < 4; ++nt) {
                bf16x8 b = *(const bf16x8*)(wb + nt * 512);
                acc[mat][nt] = __builtin_amdgcn_mfma_f32_16x16x32_bf16(
                    a, b, acc[mat][nt], 0, 0, 0);
            }
        }
    }

    float dreg[4];
#pragma unroll
    for (int r = 0; r < 4; ++r) dreg[r] = degw[r0 + lgrp * 4 + r];

#pragma unroll
    for (int nt = 0; nt < 4; ++nt) {
        int col = nt * 16 + lrow;
        float b1c = b1[col], b3c = b3[col];
#pragma unroll
        for (int r = 0; r < 4; ++r) {
            int row = r0 + lgrp * 4 + r;
            float o = acc[0][nt][r] + acc[2][nt][r] - dreg[r] * acc[1][nt][r]
                    + dreg[r] * b1c + b3c;
            o = fmaxf(o, 0.f);
            if (WRITE_BF)
                hbf_out[((size_t)row << 6) + col] = f32_to_bf16_rne(o);
            else
                hout[((size_t)row << 6) + col] = o;
        }
    }
}

// ---------------------------------------------------------------------------
extern "C" void kernel_launch(void* const* d_in, const int* in_sizes, int n_in,
                              void* d_out, int out_size, void* d_ws, size_t ws_size,
                              hipStream_t stream)
{
    const float* x    = (const float*)d_in[0];
    const int*   eidx = (const int*)  d_in[1];
    const float* attr = (const float*)d_in[2];
    const float* Wemb = (const float*)d_in[4];
    const float* bemb = (const float*)d_in[5];
    const float* W1   = (const float*)d_in[6];
    const float* b1   = (const float*)d_in[7];
    const float* W2   = (const float*)d_in[8];
    const float* W3   = (const float*)d_in[9];
    const float* b3   = (const float*)d_in[10];

    float* hout = (float*)d_out;

    // workspace layout (4B units)
    float*    degw    = (float*)d_ws;                            // N
    int*      rowptr  = (int*)d_ws + 100000;                     // N+1
    int*      tileOff = (int*)d_ws + 200016;                     // NTOT
    int2*     edgeS   = (int2*)((int*)d_ws + 250192);            // E int2
    ushort_t* hbf     = (ushort_t*)((int*)d_ws + 3450192);       // N*64 bf16
    ushort_t* aggbf   = (ushort_t*)((int*)d_ws + 6650192);       // N*64 bf16
    int2*     tmp     = (int2*)aggbf;                            // alias (CSR build)
    ushort_t* wfrag   = (ushort_t*)((int*)d_ws + 9850192);       // 49152 ushorts
    ushort_t* wefrag  = (ushort_t*)((int*)d_ws + 9874768);       // 16384 ushorts

    const int* srcI = eidx;
    const int* dstI = eidx + NEDGES;

    wprep_emb   <<<32, 256, 0, stream>>>(Wemb, wefrag);
    wprep_kernel<<<96, 256, 0, stream>>>(W1, W2, W3, wfrag);

    const int mfmaGrid = (NNODES / 16 + 3) / 4;   // 1563
    emb_mfma<<<mfmaGrid, 256, 0, stream>>>(x, wefrag, bemb, hbf);

    p1_hist<<<NT, 256, 0, stream>>>(dstI, tileOff);
    p2_scan<<<1, 1024, 0, stream>>>(tileOff);
    p3_bin <<<NT, 256, 0, stream>>>(srcI, dstI, attr, tileOff, tmp);
    p4_sort<<<NBUCK, 256, 0, stream>>>(tmp, tileOff, edgeS, rowptr);

    // layer 0: writes hbf
    gather_kernel<<<NNODES * HDIM / 256, 256, 0, stream>>>(
        rowptr, edgeS, hbf, aggbf, degw);
    dense_mfma<1><<<mfmaGrid, 256, 0, stream>>>(
        hbf, aggbf, degw, wfrag, b1, b3, hout, hbf);
    // layer 1: writes fp32 output
    gather_kernel<<<NNODES * HDIM / 256, 256, 0, stream>>>(
        rowptr, edgeS, hbf, aggbf, degw);
    dense_mfma<0><<<mfmaGrid, 256, 0, stream>>>(
        hbf, aggbf, degw, wfrag + 24576, b1 + HDIM, b3 + HDIM, hout, hbf);
}